// Round 3
// baseline (1511.035 us; speedup 1.0000x reference)
//
#include <hip/hip_runtime.h>
#include <cstdint>
#include <cstddef>

// ---------------------------------------------------------------------------
// TGN transformer attention layer, MI355X (gfx950).
// Pipeline:
//   prep   : pack weights to fp16 (pad Wkv 356->384; fold time-ones into bq)
//   hist/scan/scatter : CSR over dst; scatter emits rank[e] (CSR position)
//   k_q    : D rows : Q_ori -> Qh(f32), Kh_self, Vh_self (fp16)
//   k_kv   : persistent blocks, 64-edge tiles, double-pipelined staging:
//            X=[h|f|cos(dt*w)] -> K_ori -> Kh,Vh stored CSR-permuted (fp16)
//   k_agg  : per-dst wave: streaming segment softmax + weighted V sum +
//            relu + LayerNorm -> d_out (f32)
// ---------------------------------------------------------------------------

typedef _Float16 f16_t;
typedef _Float16 f16x8 __attribute__((ext_vector_type(8)));
typedef _Float16 f16x4 __attribute__((ext_vector_type(4)));
typedef float    f32x4 __attribute__((ext_vector_type(4)));

#define MFMA16(a, b, c) __builtin_amdgcn_mfma_f32_16x16x32_f16(a, b, c, 0, 0, 0)

static __device__ __forceinline__ f32x4 zero4() {
  f32x4 v; v[0] = 0.f; v[1] = 0.f; v[2] = 0.f; v[3] = 0.f; return v;
}

// w_j = 10^(-9 j / 99)  ->  exp2(j * (-9*log2(10)/99))
#define TIMEW_LOG2 (-0.30199346317157837f)

// ---------------------------------------------------------------------------
// prep: weight packing.  flat index ranges:
//   [0,98304)        Wkv_pad  f16 [256][384]  (zero-padded 356->384)
//   [98304,131072)   Wq_pack  f16 [256][128]  (h-columns of Wq_lin)
//   [131072,327680)  W3       f16 [768][256]  ([Wq;Wk;Wv])
//   [327680,327936)  bq_eff   f32 [256]  (bq_lin + sum of time-cols of Wq_lin)
// ---------------------------------------------------------------------------
__global__ void k_prep(const float* __restrict__ wq_lin,
                       const float* __restrict__ bq_lin,
                       const float* __restrict__ wkv_lin,
                       const float* __restrict__ wq,
                       const float* __restrict__ wk,
                       const float* __restrict__ wv,
                       f16_t* __restrict__ wkv_pad,
                       f16_t* __restrict__ wq1,
                       f16_t* __restrict__ w3,
                       float* __restrict__ bqe) {
  int i = blockIdx.x * 256 + threadIdx.x;
  if (i < 98304) {
    int o = i / 384, k = i - o * 384;
    wkv_pad[i] = (f16_t)(k < 356 ? wkv_lin[o * 356 + k] : 0.f);
  } else if (i < 131072) {
    int j = i - 98304;
    int o = j >> 7, k = j & 127;
    wq1[j] = (f16_t)wq_lin[o * 228 + k];
  } else if (i < 327680) {
    int j = i - 131072;
    int r = j >> 8, k = j & 255;
    const float* src = (r < 256) ? wq : ((r < 512) ? wk : wv);
    int rr = r & 255;
    w3[j] = (f16_t)src[rr * 256 + k];
  } else if (i < 327936) {
    int o = i - 327680;
    float s = bq_lin[o];
    for (int j = 0; j < 100; ++j) s += wq_lin[o * 228 + 128 + j];
    bqe[o] = s;
  }
}

// ---------------------------------------------------------------------------
// CSR build
// ---------------------------------------------------------------------------
__global__ void k_hist(const int* __restrict__ dst, int* __restrict__ rs, int E) {
  int e = blockIdx.x * 256 + threadIdx.x;
  if (e < E) atomicAdd(&rs[dst[e] + 1], 1);
}

__global__ void k_scan(int* __restrict__ rs, int* __restrict__ cur, int D) {
  __shared__ int sd[1024];
  __shared__ int srun;
  const int t = threadIdx.x;
  if (t == 0) srun = 0;
  __syncthreads();
  for (int base = 0; base < D; base += 1024) {
    const int i = base + t;
    int c = (i < D) ? rs[i + 1] : 0;
    sd[t] = c;
    __syncthreads();
    for (int off = 1; off < 1024; off <<= 1) {
      int v = (t >= off) ? sd[t - off] : 0;
      __syncthreads();
      sd[t] += v;
      __syncthreads();
    }
    const int incl = sd[t];
    const int run = srun;
    __syncthreads();
    if (i < D) {
      cur[i] = run + incl - c;     // exclusive prefix = cursor start
      rs[i + 1] = run + incl;      // inclusive prefix = row_start[i+1]
    }
    if (t == 1023) srun = run + sd[1023];
    __syncthreads();
  }
}

// rank[e] = CSR position of edge e (rows of khg/vhg are CSR-ordered)
__global__ void k_scatter(const int* __restrict__ dst, int* __restrict__ cur,
                          int* __restrict__ rank, int E) {
  int e = blockIdx.x * 256 + threadIdx.x;
  if (e < E) {
    int pos = atomicAdd(&cur[dst[e]], 1);
    rank[e] = pos;
  }
}

__global__ void k_sentinel(float* __restrict__ o, int n) {
  int i = blockIdx.x * 256 + threadIdx.x;
  if (i < n) o[i] = 1e30f;  // unambiguous "workspace too small" marker
}

// ---------------------------------------------------------------------------
// k_q: 64 dst rows per block, 8 waves.
//   GEMM1 (K=128): Q_ori = h[:D] @ Wq_pack^T + bq_eff     -> LDS (f16, swz)
//   GEMM2 (3 passes over W3): Qh(f32), Kh_self, Vh_self (f16)
// ---------------------------------------------------------------------------
__global__ __launch_bounds__(512) void k_q(
    const float* __restrict__ h, const float* __restrict__ bqe,
    const float* __restrict__ bq, const float* __restrict__ bk,
    const float* __restrict__ bv, const f16_t* __restrict__ wq1,
    const f16_t* __restrict__ w3, float* __restrict__ qhd,
    f16_t* __restrict__ khs, f16_t* __restrict__ vhs, int D) {
  __shared__ f16_t sm[64 * 256];
  f16_t* xs = sm;
  f16_t* ks = sm;
  const int tid = threadIdx.x;
  const int dbase = blockIdx.x * 64;

  {
    const int r = tid >> 3, q = tid & 7;
    const int dd = min(dbase + r, D - 1);
    const int sw = r & 7;
    const float* p = h + (size_t)dd * 128 + q * 16;
#pragma unroll
    for (int u = 0; u < 2; ++u) {
      float4 v0 = *(const float4*)(p + u * 8);
      float4 v1 = *(const float4*)(p + u * 8 + 4);
      f16x8 w8;
      w8[0] = (f16_t)v0.x; w8[1] = (f16_t)v0.y; w8[2] = (f16_t)v0.z; w8[3] = (f16_t)v0.w;
      w8[4] = (f16_t)v1.x; w8[5] = (f16_t)v1.y; w8[6] = (f16_t)v1.z; w8[7] = (f16_t)v1.w;
      *(f16x8*)&xs[r * 128 + (((2 * q + u) ^ sw) << 3)] = w8;
    }
  }
  __syncthreads();

  const int lane = tid & 63;
  const int wv_ = tid >> 6;
  const int m16 = lane & 15;
  const int g = lane >> 4;

  f32x4 acc1[4][2];
#pragma unroll
  for (int mt = 0; mt < 4; ++mt)
#pragma unroll
    for (int nt = 0; nt < 2; ++nt) acc1[mt][nt] = zero4();

#pragma unroll
  for (int kt = 0; kt < 4; ++kt) {
    f16x8 a[4];
#pragma unroll
    for (int mt = 0; mt < 4; ++mt) {
      int row = mt * 16 + m16;
      a[mt] = *(const f16x8*)&xs[row * 128 + ((((kt << 2) + g) ^ (row & 7)) << 3)];
    }
#pragma unroll
    for (int nt = 0; nt < 2; ++nt) {
      int col = wv_ * 32 + nt * 16 + m16;
      f16x8 b = *(const f16x8*)&wq1[(size_t)col * 128 + (kt << 5) + (g << 3)];
#pragma unroll
      for (int mt = 0; mt < 4; ++mt) acc1[mt][nt] = MFMA16(a[mt], b, acc1[mt][nt]);
    }
  }
  __syncthreads();

#pragma unroll
  for (int nt = 0; nt < 2; ++nt) {
    int col = wv_ * 32 + nt * 16 + m16;
    float bias = bqe[col];
#pragma unroll
    for (int mt = 0; mt < 4; ++mt)
#pragma unroll
      for (int j = 0; j < 4; ++j) {
        int row = mt * 16 + (g << 2) + j;
        ks[row * 256 + ((((col >> 3) ^ (row & 7)) << 3)) + (col & 7)] =
            (f16_t)(acc1[mt][nt][j] + bias);
      }
  }
  __syncthreads();

#pragma unroll
  for (int p = 0; p < 3; ++p) {
    const f16_t* wsec = w3 + ((size_t)p << 16);
    const float* bsec = (p == 0) ? bq : ((p == 1) ? bk : bv);
    f32x4 acc[4][2];
#pragma unroll
    for (int mt = 0; mt < 4; ++mt)
#pragma unroll
      for (int nt = 0; nt < 2; ++nt) acc[mt][nt] = zero4();
#pragma unroll
    for (int kt = 0; kt < 8; ++kt) {
      f16x8 a[4];
#pragma unroll
      for (int mt = 0; mt < 4; ++mt) {
        int row = mt * 16 + m16;
        a[mt] = *(const f16x8*)&ks[row * 256 + ((((kt << 2) + g) ^ (row & 7)) << 3)];
      }
#pragma unroll
      for (int nt = 0; nt < 2; ++nt) {
        int col = wv_ * 32 + nt * 16 + m16;
        f16x8 b = *(const f16x8*)&wsec[(size_t)col * 256 + (kt << 5) + (g << 3)];
#pragma unroll
        for (int mt = 0; mt < 4; ++mt) acc[mt][nt] = MFMA16(a[mt], b, acc[mt][nt]);
      }
    }
#pragma unroll
    for (int nt = 0; nt < 2; ++nt) {
      int col = wv_ * 32 + nt * 16 + m16;
      float bias = bsec[col];
#pragma unroll
      for (int mt = 0; mt < 4; ++mt)
#pragma unroll
        for (int j = 0; j < 4; ++j) {
          int row = mt * 16 + (g << 2) + j;
          int dd = dbase + row;
          if (dd < D) {
            float val = acc[mt][nt][j] + bias;
            if (p == 0)
              qhd[(size_t)dd * 256 + col] = val;
            else if (p == 1)
              khs[(size_t)dd * 256 + col] = (f16_t)val;
            else
              vhs[(size_t)dd * 256 + col] = (f16_t)val;
          }
        }
    }
  }
}

// ---------------------------------------------------------------------------
// k_kv: PERSISTENT blocks (2/CU), 8 waves, 64-edge tiles, grid-stride loop.
//   Tile t+1's global loads are issued during tile t's compute (T14 split) so
//   HBM latency hides under GEMM1+GEMM2.  xs and ks are separate LDS regions
//   (80 KB total -> 2 blocks/CU) so resident blocks' phases interleave.
//   GEMM2 merged: one pass over stacked [Wk;Wv] (wave owns 64 of 512 cols).
//   Kh/Vh rows stored CSR-permuted via rank[] so k_agg streams.
// ---------------------------------------------------------------------------
__global__ __launch_bounds__(512) void k_kv(
    const float* __restrict__ h, const float* __restrict__ f,
    const float* __restrict__ dt, const float* __restrict__ bkv,
    const float* __restrict__ bk, const float* __restrict__ bv,
    const f16_t* __restrict__ wkv, const f16_t* __restrict__ w3,
    const int* __restrict__ rank, f16_t* __restrict__ khg,
    f16_t* __restrict__ vhg, int D, int E, int ntiles) {
  __shared__ f16_t xs[64 * 384];
  __shared__ f16_t ks[64 * 256];
  const int tid = threadIdx.x;
  const int r = tid >> 3, q = tid & 7;
  const int sw = r & 7;
  const int lane = tid & 63;
  const int wv_ = tid >> 6;
  const int m16 = lane & 15;
  const int g = lane >> 4;

  // staging registers (tile t's data, loaded one iteration ahead)
  float4 ha0, ha1, hb0, hb1, fa0, fa1, fb0, fb1;
  float dtv;

  int tile = blockIdx.x;
  if (tile < ntiles) {
    int e = min(tile * 64 + r, E - 1);
    const float* ph = h + (size_t)(D + e) * 128 + q * 16;
    ha0 = *(const float4*)(ph + 0);  ha1 = *(const float4*)(ph + 4);
    hb0 = *(const float4*)(ph + 8);  hb1 = *(const float4*)(ph + 12);
    const float* pf = f + (size_t)e * 128 + q * 16;
    fa0 = *(const float4*)(pf + 0);  fa1 = *(const float4*)(pf + 4);
    fb0 = *(const float4*)(pf + 8);  fb1 = *(const float4*)(pf + 12);
    dtv = dt[e];
  }

  for (; tile < ntiles; tile += gridDim.x) {
    const int ebase = tile * 64;

    // ---- write xs from registers (h | f | time features)
    {
      f16x8 w8;
      w8[0] = (f16_t)ha0.x; w8[1] = (f16_t)ha0.y; w8[2] = (f16_t)ha0.z; w8[3] = (f16_t)ha0.w;
      w8[4] = (f16_t)ha1.x; w8[5] = (f16_t)ha1.y; w8[6] = (f16_t)ha1.z; w8[7] = (f16_t)ha1.w;
      *(f16x8*)&xs[r * 384 + (((2 * q + 0) ^ sw) << 3)] = w8;
      w8[0] = (f16_t)hb0.x; w8[1] = (f16_t)hb0.y; w8[2] = (f16_t)hb0.z; w8[3] = (f16_t)hb0.w;
      w8[4] = (f16_t)hb1.x; w8[5] = (f16_t)hb1.y; w8[6] = (f16_t)hb1.z; w8[7] = (f16_t)hb1.w;
      *(f16x8*)&xs[r * 384 + (((2 * q + 1) ^ sw) << 3)] = w8;
      w8[0] = (f16_t)fa0.x; w8[1] = (f16_t)fa0.y; w8[2] = (f16_t)fa0.z; w8[3] = (f16_t)fa0.w;
      w8[4] = (f16_t)fa1.x; w8[5] = (f16_t)fa1.y; w8[6] = (f16_t)fa1.z; w8[7] = (f16_t)fa1.w;
      *(f16x8*)&xs[r * 384 + (((16 + 2 * q + 0) ^ sw) << 3)] = w8;
      w8[0] = (f16_t)fb0.x; w8[1] = (f16_t)fb0.y; w8[2] = (f16_t)fb0.z; w8[3] = (f16_t)fb0.w;
      w8[4] = (f16_t)fb1.x; w8[5] = (f16_t)fb1.y; w8[6] = (f16_t)fb1.z; w8[7] = (f16_t)fb1.w;
      *(f16x8*)&xs[r * 384 + (((16 + 2 * q + 1) ^ sw) << 3)] = w8;
#pragma unroll
      for (int c = q; c < 128; c += 8) {
        float val = 0.f;
        if (c < 100) {
          float wj = exp2f(TIMEW_LOG2 * (float)c);
          val = __cosf(dtv * wj);
        }
        int col = 256 + c;
        xs[r * 384 + ((((col >> 3) ^ sw)) << 3) + (col & 7)] = (f16_t)val;
      }
    }

    // ---- issue next tile's global loads now (latency hides under GEMMs)
    {
      int nt_ = tile + gridDim.x;
      if (nt_ < ntiles) {
        int e = min(nt_ * 64 + r, E - 1);
        const float* ph = h + (size_t)(D + e) * 128 + q * 16;
        ha0 = *(const float4*)(ph + 0);  ha1 = *(const float4*)(ph + 4);
        hb0 = *(const float4*)(ph + 8);  hb1 = *(const float4*)(ph + 12);
        const float* pf = f + (size_t)e * 128 + q * 16;
        fa0 = *(const float4*)(pf + 0);  fa1 = *(const float4*)(pf + 4);
        fb0 = *(const float4*)(pf + 8);  fb1 = *(const float4*)(pf + 12);
        dtv = dt[e];
      }
    }
    __syncthreads();

    // ---- GEMM1: K = 384 (12 k-steps), 256 output cols
    f32x4 acc1[4][2];
#pragma unroll
    for (int mt = 0; mt < 4; ++mt)
#pragma unroll
      for (int nt = 0; nt < 2; ++nt) acc1[mt][nt] = zero4();

#pragma unroll
    for (int kt = 0; kt < 12; ++kt) {
      f16x8 a[4];
#pragma unroll
      for (int mt = 0; mt < 4; ++mt) {
        int row = mt * 16 + m16;
        a[mt] = *(const f16x8*)&xs[row * 384 + ((((kt << 2) + g) ^ (row & 7)) << 3)];
      }
#pragma unroll
      for (int nt = 0; nt < 2; ++nt) {
        int col = wv_ * 32 + nt * 16 + m16;
        f16x8 b = *(const f16x8*)&wkv[(size_t)col * 384 + (kt << 5) + (g << 3)];
#pragma unroll
        for (int mt = 0; mt < 4; ++mt) acc1[mt][nt] = MFMA16(a[mt], b, acc1[mt][nt]);
      }
    }
    __syncthreads();  // all xs reads done; all prior GEMM2 ks reads done

    // ---- write K_ori tile (f16, swizzled) + bkv bias
#pragma unroll
    for (int nt = 0; nt < 2; ++nt) {
      int col = wv_ * 32 + nt * 16 + m16;
      float bias = bkv[col];
#pragma unroll
      for (int mt = 0; mt < 4; ++mt)
#pragma unroll
        for (int j = 0; j < 4; ++j) {
          int row = mt * 16 + (g << 2) + j;
          ks[row * 256 + ((((col >> 3) ^ (row & 7)) << 3)) + (col & 7)] =
              (f16_t)(acc1[mt][nt][j] + bias);
        }
    }
    __syncthreads();

    // ---- GEMM2 merged: cols 0..511 of [Wk;Wv] (w3 rows 256..767)
    f32x4 acc2[4][4];
#pragma unroll
    for (int mt = 0; mt < 4; ++mt)
#pragma unroll
      for (int nt2 = 0; nt2 < 4; ++nt2) acc2[mt][nt2] = zero4();

#pragma unroll
    for (int kt = 0; kt < 8; ++kt) {
      f16x8 a[4];
#pragma unroll
      for (int mt = 0; mt < 4; ++mt) {
        int row = mt * 16 + m16;
        a[mt] = *(const f16x8*)&ks[row * 256 + ((((kt << 2) + g) ^ (row & 7)) << 3)];
      }
#pragma unroll
      for (int nt2 = 0; nt2 < 4; ++nt2) {
        int col512 = wv_ * 64 + nt2 * 16 + m16;
        f16x8 b = *(const f16x8*)&w3[(size_t)(256 + col512) * 256 + (kt << 5) + (g << 3)];
#pragma unroll
        for (int mt = 0; mt < 4; ++mt) acc2[mt][nt2] = MFMA16(a[mt], b, acc2[mt][nt2]);
      }
    }

    // ---- store Kh/Vh at CSR-permuted rows
    float bs[4];
#pragma unroll
    for (int nt2 = 0; nt2 < 4; ++nt2) {
      int col512 = wv_ * 64 + nt2 * 16 + m16;
      bs[nt2] = (col512 < 256) ? bk[col512] : bv[col512 - 256];
    }
#pragma unroll
    for (int mt = 0; mt < 4; ++mt)
#pragma unroll
      for (int j = 0; j < 4; ++j) {
        int row = mt * 16 + (g << 2) + j;
        int e2 = ebase + row;
        if (e2 < E) {
          size_t rb = (size_t)rank[e2] * 256;
#pragma unroll
          for (int nt2 = 0; nt2 < 4; ++nt2) {
            int col512 = wv_ * 64 + nt2 * 16 + m16;
            float val = acc2[mt][nt2][j] + bs[nt2];
            if (col512 < 256)
              khg[rb + col512] = (f16_t)val;
            else
              vhg[rb + (col512 - 256)] = (f16_t)val;
          }
        }
      }
  }
}

// ---------------------------------------------------------------------------
// k_agg: one wave per dst node; K/V rows are CSR-ordered -> streaming reads.
// Softmax without max-shift (mathematically identical to the reference).
// Fused: segment softmax + weighted V sum + relu + LayerNorm.
// ---------------------------------------------------------------------------
__global__ __launch_bounds__(256) void k_agg(
    const float* __restrict__ qhd, const f16_t* __restrict__ khs,
    const f16_t* __restrict__ vhs, const f16_t* __restrict__ khg,
    const f16_t* __restrict__ vhg, const int* __restrict__ rs,
    const float* __restrict__ lng, const float* __restrict__ lnb,
    float* __restrict__ out, int D) {
  const int lane = threadIdx.x & 63;
  const int d = blockIdx.x * 4 + (threadIdx.x >> 6);
  if (d >= D) return;
  const int c0 = lane * 4;

  float qh0, qh1, qh2, qh3;
  {
    float4 v = *(const float4*)(qhd + (size_t)d * 256 + c0);
    qh0 = v.x; qh1 = v.y; qh2 = v.z; qh3 = v.w;
  }

  // self-loop term
  float den, a0, a1, a2, a3;
  {
    f16x4 ku = *(const f16x4*)(khs + (size_t)d * 256 + c0);
    f16x4 vu = *(const f16x4*)(vhs + (size_t)d * 256 + c0);
    float s = qh0 * (float)ku[0] + qh1 * (float)ku[1] + qh2 * (float)ku[2] + qh3 * (float)ku[3];
    s += __shfl_xor(s, 1); s += __shfl_xor(s, 2); s += __shfl_xor(s, 4);
    s = (s > 0.f) ? s : 0.2f * s;
    float ee = __expf(s);
    den = ee;
    a0 = ee * (float)vu[0]; a1 = ee * (float)vu[1];
    a2 = ee * (float)vu[2]; a3 = ee * (float)vu[3];
  }

  const int beg = rs[d], end = rs[d + 1];
  f16x4 kN, vN;
  if (beg < end) {
    kN = *(const f16x4*)(khg + (size_t)beg * 256 + c0);
    vN = *(const f16x4*)(vhg + (size_t)beg * 256 + c0);
  }
  for (int idx = beg; idx < end; ++idx) {
    f16x4 ku = kN, vu = vN;
    if (idx + 1 < end) {  // 1-deep prefetch (sequential rows)
      kN = *(const f16x4*)(khg + (size_t)(idx + 1) * 256 + c0);
      vN = *(const f16x4*)(vhg + (size_t)(idx + 1) * 256 + c0);
    }
    float s = qh0 * (float)ku[0] + qh1 * (float)ku[1] + qh2 * (float)ku[2] + qh3 * (float)ku[3];
    s += __shfl_xor(s, 1); s += __shfl_xor(s, 2); s += __shfl_xor(s, 4);
    s = (s > 0.f) ? s : 0.2f * s;
    float ee = __expf(s);
    den += ee;
    a0 = fmaf(ee, (float)vu[0], a0); a1 = fmaf(ee, (float)vu[1], a1);
    a2 = fmaf(ee, (float)vu[2], a2); a3 = fmaf(ee, (float)vu[3], a3);
  }

  float x0 = fmaxf(a0 / den, 0.f), x1 = fmaxf(a1 / den, 0.f);
  float x2 = fmaxf(a2 / den, 0.f), x3 = fmaxf(a3 / den, 0.f);

  float s1 = x0 + x1 + x2 + x3;
#pragma unroll
  for (int m = 1; m < 64; m <<= 1) s1 += __shfl_xor(s1, m);
  float mu = s1 * (1.f / 256.f);
  float d0 = x0 - mu, d1 = x1 - mu, d2 = x2 - mu, d3 = x3 - mu;
  float s2 = d0 * d0 + d1 * d1 + d2 * d2 + d3 * d3;
#pragma unroll
  for (int m = 1; m < 64; m <<= 1) s2 += __shfl_xor(s2, m);
  float rstd = rsqrtf(s2 * (1.f / 256.f) + 1e-5f);

  float4 gg = *(const float4*)(lng + c0);
  float4 bb = *(const float4*)(lnb + c0);
  float4 o;
  o.x = d0 * rstd * gg.x + bb.x;
  o.y = d1 * rstd * gg.y + bb.y;
  o.z = d2 * rstd * gg.z + bb.z;
  o.w = d3 * rstd * gg.w + bb.w;
  *(float4*)(out + (size_t)d * 256 + c0) = o;
}

// ---------------------------------------------------------------------------
extern "C" void kernel_launch(void* const* d_in, const int* in_sizes, int n_in,
                              void* d_out, int out_size, void* d_ws,
                              size_t ws_size, hipStream_t stream) {
  const float* h       = (const float*)d_in[0];
  const float* f       = (const float*)d_in[1];
  const float* dt      = (const float*)d_in[2];
  const float* wq_lin  = (const float*)d_in[3];
  const float* bq_lin  = (const float*)d_in[4];
  const float* wkv_lin = (const float*)d_in[5];
  const float* bkv_lin = (const float*)d_in[6];
  const float* wq      = (const float*)d_in[7];
  const float* bq      = (const float*)d_in[8];
  const float* wk      = (const float*)d_in[9];
  const float* bk      = (const float*)d_in[10];
  const float* wv      = (const float*)d_in[11];
  const float* bv      = (const float*)d_in[12];
  const float* lng     = (const float*)d_in[13];
  const float* lnb     = (const float*)d_in[14];
  const int*   dst     = (const int*)d_in[15];

  const int S = in_sizes[0] / 128;
  const int E = in_sizes[2];
  const int D = S - E;
  float* out = (float*)d_out;

  // workspace carve-out (256B aligned)
  char* p = (char*)d_ws;
  size_t off = 0;
  auto take = [&](size_t bytes) -> char* {
    char* r = p + off;
    off += (bytes + 255) & ~(size_t)255;
    return r;
  };
  f16_t* wkv_pad = (f16_t*)take((size_t)98304 * 2);
  f16_t* wq1     = (f16_t*)take((size_t)32768 * 2);
  f16_t* w3      = (f16_t*)take((size_t)196608 * 2);
  float* bqe     = (float*)take((size_t)256 * 4);
  float* qhd     = (float*)take((size_t)D * 256 * 4);
  f16_t* khs     = (f16_t*)take((size_t)D * 256 * 2);
  f16_t* vhs     = (f16_t*)take((size_t)D * 256 * 2);
  f16_t* khg     = (f16_t*)take((size_t)E * 256 * 2);
  f16_t* vhg     = (f16_t*)take((size_t)E * 256 * 2);
  int*   rs      = (int*)  take((size_t)(D + 1) * 4);
  int*   cur     = (int*)  take((size_t)D * 4);
  int*   rank    = (int*)  take((size_t)E * 4);

  if (off > ws_size) {
    k_sentinel<<<(out_size + 255) / 256, 256, 0, stream>>>(out, out_size);
    return;
  }

  const int ntiles = (E + 63) / 64;

  hipMemsetAsync(rs, 0, (size_t)(D + 1) * 4, stream);
  k_prep<<<1281, 256, 0, stream>>>(wq_lin, bq_lin, wkv_lin, wq, wk, wv,
                                   wkv_pad, wq1, w3, bqe);
  k_hist<<<(E + 255) / 256, 256, 0, stream>>>(dst, rs, E);
  k_scan<<<1, 1024, 0, stream>>>(rs, cur, D);
  k_scatter<<<(E + 255) / 256, 256, 0, stream>>>(dst, cur, rank, E);
  k_q<<<(D + 63) / 64, 512, 0, stream>>>(h, bqe, bq, bk, bv, wq1, w3, qhd, khs,
                                         vhs, D);
  k_kv<<<512, 512, 0, stream>>>(h, f, dt, bkv_lin, bk, bv, wkv_pad, w3, rank,
                                khg, vhg, D, E, ntiles);
  k_agg<<<(D + 3) / 4, 256, 0, stream>>>(qhd, khs, vhs, khg, vhg, rs, lng, lnb,
                                         out, D);
}

// Round 4
// 906.987 us; speedup vs baseline: 1.6660x; 1.6660x over previous
//
#include <hip/hip_runtime.h>
#include <cstdint>
#include <cstddef>

// ---------------------------------------------------------------------------
// TGN transformer attention layer, MI355X (gfx950).
//   k_prep  : pack k_q weights to f16; bq_eff (time-ones folded)
//   k_wcomp : compose Weff = [Wk;Wv] @ Wkv (f32) -> f16, fragment-packed;
//             beff = [Wk;Wv]@bkv + [bk;bv]   (GEMM2 eliminated algebraically)
//   CSR     : hist/scan/scatter over dst
//   k_q     : D rows: Q_ori -> Qh(f32), Kh_self, Vh_self (f16)
//   k_kv    : single GEMM  C[E x 512] = X[E x 384] @ Weff^T + beff,
//             X=[h|f|cos(dt*w)] built on the fly; BM=128 BN=512 BK=32,
//             16 waves, A/B LDS double-buffered, 1 barrier/chunk
//   k_agg   : per-dst wave: segment softmax + weighted V sum + relu + LN
// ---------------------------------------------------------------------------

typedef _Float16 f16_t;
typedef _Float16 f16x8 __attribute__((ext_vector_type(8)));
typedef _Float16 f16x4 __attribute__((ext_vector_type(4)));
typedef float    f32x4 __attribute__((ext_vector_type(4)));

#define MFMA16(a, b, c) __builtin_amdgcn_mfma_f32_16x16x32_f16(a, b, c, 0, 0, 0)

static __device__ __forceinline__ f32x4 zero4() {
  f32x4 v; v[0] = 0.f; v[1] = 0.f; v[2] = 0.f; v[3] = 0.f; return v;
}

// w_j = 10^(-9 j / 99)  ->  exp2(j * (-9*log2(10)/99))
#define TIMEW_LOG2 (-0.30199346317157837f)

// ---------------------------------------------------------------------------
// prep (k_q weights only):
//   [0,32768)        Wq_pack f16 [256][128]  (h-columns of Wq_lin)
//   [32768,229376)   W3      f16 [768][256]  ([Wq;Wk;Wv])
//   [229376,229632)  bq_eff  f32 [256]
// ---------------------------------------------------------------------------
__global__ void k_prep(const float* __restrict__ wq_lin,
                       const float* __restrict__ bq_lin,
                       const float* __restrict__ wq,
                       const float* __restrict__ wk,
                       const float* __restrict__ wv,
                       f16_t* __restrict__ wq1,
                       f16_t* __restrict__ w3,
                       float* __restrict__ bqe) {
  int i = blockIdx.x * 256 + threadIdx.x;
  if (i < 32768) {
    int o = i >> 7, k = i & 127;
    wq1[i] = (f16_t)wq_lin[o * 228 + k];
  } else if (i < 229376) {
    int j = i - 32768;
    int r = j >> 8, k = j & 255;
    const float* src = (r < 256) ? wq : ((r < 512) ? wk : wv);
    w3[j] = (f16_t)src[(r & 255) * 256 + k];
  } else if (i < 229632) {
    int o = i - 229376;
    float s = bq_lin[o];
    for (int j = 0; j < 100; ++j) s += wq_lin[o * 228 + 128 + j];
    bqe[o] = s;
  }
}

// ---------------------------------------------------------------------------
// k_wcomp: one block per output channel oc of [Kh;Vh] (512 blocks).
//   Weff[oc][c] = sum_m W23[oc][m] * Wkv[m][c]   (c<356; 0-pad to 384)
//   packed fragment layout: idx = kc*16384 + g*4096 + oc*8 + j
//     where kc=c>>5, g=(c>>3)&3, j=c&7   (matches k_kv LDS layout)
// ---------------------------------------------------------------------------
__global__ __launch_bounds__(384) void k_wcomp(
    const float* __restrict__ wkv_lin, const float* __restrict__ bkv,
    const float* __restrict__ wk, const float* __restrict__ bk,
    const float* __restrict__ wv, const float* __restrict__ bv,
    f16_t* __restrict__ weffp, float* __restrict__ beff) {
  __shared__ float wrow[256];
  const int oc = blockIdx.x;
  const float* src = (oc < 256) ? (wk + (size_t)oc * 256)
                                : (wv + (size_t)(oc - 256) * 256);
  const int t = threadIdx.x;
  if (t < 256) wrow[t] = src[t];
  __syncthreads();

  float acc = 0.f;
  if (t < 356) {
#pragma unroll 4
    for (int m = 0; m < 256; ++m) acc += wrow[m] * wkv_lin[(size_t)m * 356 + t];
  }
  int kc = t >> 5, g = (t >> 3) & 3, j = t & 7;
  weffp[(size_t)kc * 16384 + g * 4096 + oc * 8 + j] = (f16_t)acc;

  if (t == 0) {
    float b = (oc < 256) ? bk[oc] : bv[oc - 256];
    for (int m = 0; m < 256; ++m) b += wrow[m] * bkv[m];
    beff[oc] = b;
  }
}

// ---------------------------------------------------------------------------
// CSR build
// ---------------------------------------------------------------------------
__global__ void k_hist(const int* __restrict__ dst, int* __restrict__ rs, int E) {
  int e = blockIdx.x * 256 + threadIdx.x;
  if (e < E) atomicAdd(&rs[dst[e] + 1], 1);
}

__global__ void k_scan(int* __restrict__ rs, int* __restrict__ cur, int D) {
  __shared__ int sd[1024];
  __shared__ int srun;
  const int t = threadIdx.x;
  if (t == 0) srun = 0;
  __syncthreads();
  for (int base = 0; base < D; base += 1024) {
    const int i = base + t;
    int c = (i < D) ? rs[i + 1] : 0;
    sd[t] = c;
    __syncthreads();
    for (int off = 1; off < 1024; off <<= 1) {
      int v = (t >= off) ? sd[t - off] : 0;
      __syncthreads();
      sd[t] += v;
      __syncthreads();
    }
    const int incl = sd[t];
    const int run = srun;
    __syncthreads();
    if (i < D) {
      cur[i] = run + incl - c;
      rs[i + 1] = run + incl;
    }
    if (t == 1023) srun = run + sd[1023];
    __syncthreads();
  }
}

__global__ void k_scatter(const int* __restrict__ dst, int* __restrict__ cur,
                          int* __restrict__ csr, int E) {
  int e = blockIdx.x * 256 + threadIdx.x;
  if (e < E) {
    int pos = atomicAdd(&cur[dst[e]], 1);
    csr[pos] = e;
  }
}

__global__ void k_sentinel(float* __restrict__ o, int n) {
  int i = blockIdx.x * 256 + threadIdx.x;
  if (i < n) o[i] = 1e30f;
}

// ---------------------------------------------------------------------------
// k_q: 64 dst rows per block, 8 waves (small kernel, D=25k rows).
// ---------------------------------------------------------------------------
__global__ __launch_bounds__(512) void k_q(
    const float* __restrict__ h, const float* __restrict__ bqe,
    const float* __restrict__ bq, const float* __restrict__ bk,
    const float* __restrict__ bv, const f16_t* __restrict__ wq1,
    const f16_t* __restrict__ w3, float* __restrict__ qhd,
    f16_t* __restrict__ khs, f16_t* __restrict__ vhs, int D) {
  __shared__ f16_t sm[64 * 256];
  f16_t* xs = sm;
  f16_t* ks = sm;
  const int tid = threadIdx.x;
  const int dbase = blockIdx.x * 64;

  {
    const int r = tid >> 3, q = tid & 7;
    const int dd = min(dbase + r, D - 1);
    const int sw = r & 7;
    const float* p = h + (size_t)dd * 128 + q * 16;
#pragma unroll
    for (int u = 0; u < 2; ++u) {
      float4 v0 = *(const float4*)(p + u * 8);
      float4 v1 = *(const float4*)(p + u * 8 + 4);
      f16x8 w8;
      w8[0] = (f16_t)v0.x; w8[1] = (f16_t)v0.y; w8[2] = (f16_t)v0.z; w8[3] = (f16_t)v0.w;
      w8[4] = (f16_t)v1.x; w8[5] = (f16_t)v1.y; w8[6] = (f16_t)v1.z; w8[7] = (f16_t)v1.w;
      *(f16x8*)&xs[r * 128 + (((2 * q + u) ^ sw) << 3)] = w8;
    }
  }
  __syncthreads();

  const int lane = tid & 63;
  const int wv_ = tid >> 6;
  const int m16 = lane & 15;
  const int g = lane >> 4;

  f32x4 acc1[4][2];
#pragma unroll
  for (int mt = 0; mt < 4; ++mt)
#pragma unroll
    for (int nt = 0; nt < 2; ++nt) acc1[mt][nt] = zero4();

#pragma unroll
  for (int kt = 0; kt < 4; ++kt) {
    f16x8 a[4];
#pragma unroll
    for (int mt = 0; mt < 4; ++mt) {
      int row = mt * 16 + m16;
      a[mt] = *(const f16x8*)&xs[row * 128 + ((((kt << 2) + g) ^ (row & 7)) << 3)];
    }
#pragma unroll
    for (int nt = 0; nt < 2; ++nt) {
      int col = wv_ * 32 + nt * 16 + m16;
      f16x8 b = *(const f16x8*)&wq1[(size_t)col * 128 + (kt << 5) + (g << 3)];
#pragma unroll
      for (int mt = 0; mt < 4; ++mt) acc1[mt][nt] = MFMA16(a[mt], b, acc1[mt][nt]);
    }
  }
  __syncthreads();

#pragma unroll
  for (int nt = 0; nt < 2; ++nt) {
    int col = wv_ * 32 + nt * 16 + m16;
    float bias = bqe[col];
#pragma unroll
    for (int mt = 0; mt < 4; ++mt)
#pragma unroll
      for (int j = 0; j < 4; ++j) {
        int row = mt * 16 + (g << 2) + j;
        ks[row * 256 + ((((col >> 3) ^ (row & 7)) << 3)) + (col & 7)] =
            (f16_t)(acc1[mt][nt][j] + bias);
      }
  }
  __syncthreads();

#pragma unroll
  for (int p = 0; p < 3; ++p) {
    const f16_t* wsec = w3 + ((size_t)p << 16);
    const float* bsec = (p == 0) ? bq : ((p == 1) ? bk : bv);
    f32x4 acc[4][2];
#pragma unroll
    for (int mt = 0; mt < 4; ++mt)
#pragma unroll
      for (int nt = 0; nt < 2; ++nt) acc[mt][nt] = zero4();
#pragma unroll
    for (int kt = 0; kt < 8; ++kt) {
      f16x8 a[4];
#pragma unroll
      for (int mt = 0; mt < 4; ++mt) {
        int row = mt * 16 + m16;
        a[mt] = *(const f16x8*)&ks[row * 256 + ((((kt << 2) + g) ^ (row & 7)) << 3)];
      }
#pragma unroll
      for (int nt = 0; nt < 2; ++nt) {
        int col = wv_ * 32 + nt * 16 + m16;
        f16x8 b = *(const f16x8*)&wsec[(size_t)col * 256 + (kt << 5) + (g << 3)];
#pragma unroll
        for (int mt = 0; mt < 4; ++mt) acc[mt][nt] = MFMA16(a[mt], b, acc[mt][nt]);
      }
    }
#pragma unroll
    for (int nt = 0; nt < 2; ++nt) {
      int col = wv_ * 32 + nt * 16 + m16;
      float bias = bsec[col];
#pragma unroll
      for (int mt = 0; mt < 4; ++mt)
#pragma unroll
        for (int j = 0; j < 4; ++j) {
          int row = mt * 16 + (g << 2) + j;
          int dd = dbase + row;
          if (dd < D) {
            float val = acc[mt][nt][j] + bias;
            if (p == 0)
              qhd[(size_t)dd * 256 + col] = val;
            else if (p == 1)
              khs[(size_t)dd * 256 + col] = (f16_t)val;
            else
              vhs[(size_t)dd * 256 + col] = (f16_t)val;
          }
        }
    }
  }
}

// ---------------------------------------------------------------------------
// k_kv: C[E x 512] = X[E x 384] @ Weff^T + beff
//   BM=128 rows/block, BN=512 (all cols), BK=32, 1024 threads = 16 waves
//   waves: wm = wid>>3 (2 x 64 rows), wn = wid&7 (8 x 64 cols)
//   LDS: A dbuf 2x8KB [u][row][8], B dbuf 2x32KB [g][col][8] = 80 KB
//   one barrier per k-chunk; next chunk's global loads issued before MFMAs
// ---------------------------------------------------------------------------
__global__ __launch_bounds__(1024, 4) void k_kv(
    const float* __restrict__ h, const float* __restrict__ f,
    const float* __restrict__ dt, const f16_t* __restrict__ weffp,
    const float* __restrict__ beff, f16_t* __restrict__ khg,
    f16_t* __restrict__ vhg, int D, int E) {
  __shared__ f16_t Ab[2][4096];    // [buf][u*1024 + row*8 + j]
  __shared__ f16_t Bb[2][16384];   // [buf][g*4096 + col*8 + j]

  const int tid = threadIdx.x;
  const int ebase = blockIdx.x * 128;

  // staging mapping: row = tid>>3 (128 rows), 4 cols per thread
  const int arow = tid >> 3;
  const int ac4 = (tid & 7) * 4;          // 0,4,...,28
  const int au = ac4 >> 3;                // 16B unit 0..3
  const int ahalf = (ac4 >> 2) & 1;
  const int ae = min(ebase + arow, E - 1);
  const float dtv = dt[ae];

  float4 aST;
  uint4 bST0, bST1;

  auto a_load = [&](int kc) -> float4 {
    if (kc < 4) {
      return *(const float4*)(h + (size_t)(D + ae) * 128 + kc * 32 + ac4);
    } else if (kc < 8) {
      return *(const float4*)(f + (size_t)ae * 128 + (kc - 4) * 32 + ac4);
    } else {
      float4 v;
      int cb = (kc - 8) * 32 + ac4;
#pragma unroll
      for (int j = 0; j < 4; ++j) {
        int c = cb + j;
        float val = 0.f;
        if (c < 100) val = __cosf(dtv * exp2f(TIMEW_LOG2 * (float)c));
        ((float*)&v)[j] = val;
      }
      return v;
    }
  };
  auto b_load = [&](int kc) {
    const uint4* src = (const uint4*)(weffp + (size_t)kc * 16384);
    bST0 = src[tid];
    bST1 = src[tid + 1024];
  };
  auto a_store = [&](int buf, float4 v) {
    f16x4 w;
    w[0] = (f16_t)v.x; w[1] = (f16_t)v.y; w[2] = (f16_t)v.z; w[3] = (f16_t)v.w;
    *(f16x4*)&Ab[buf][au * 1024 + arow * 8 + ahalf * 4] = w;
  };
  auto b_store = [&](int buf) {
    *(uint4*)&Bb[buf][tid * 8] = bST0;
    *(uint4*)&Bb[buf][8192 + tid * 8] = bST1;
  };

  // prologue: stage chunk 0
  aST = a_load(0);
  b_load(0);
  a_store(0, aST);
  b_store(0);

  const int lane = tid & 63, wid = tid >> 6;
  const int wm = wid >> 3, wn = wid & 7;
  const int m16 = lane & 15, g = lane >> 4;

  f32x4 acc[4][4];
#pragma unroll
  for (int mt = 0; mt < 4; ++mt)
#pragma unroll
    for (int n = 0; n < 4; ++n) acc[mt][n] = zero4();

  __syncthreads();

  for (int kc = 0; kc < 12; ++kc) {
    const int cur = kc & 1, nxt = cur ^ 1;
    if (kc < 11) {
      aST = a_load(kc + 1);
      b_load(kc + 1);
    }
    f16x8 afr[4];
#pragma unroll
    for (int mt = 0; mt < 4; ++mt)
      afr[mt] = *(const f16x8*)&Ab[cur][g * 1024 + (wm * 64 + mt * 16 + m16) * 8];
#pragma unroll
    for (int n = 0; n < 4; ++n) {
      f16x8 bfr = *(const f16x8*)&Bb[cur][g * 4096 + (wn * 64 + n * 16 + m16) * 8];
#pragma unroll
      for (int mt = 0; mt < 4; ++mt) acc[mt][n] = MFMA16(afr[mt], bfr, acc[mt][n]);
    }
    if (kc < 11) {
      a_store(nxt, aST);
      b_store(nxt);
    }
    __syncthreads();
  }

  // epilogue: bias + store (Kh cols 0..255, Vh cols 256..511), e-ordered
#pragma unroll
  for (int n = 0; n < 4; ++n) {
    int col = wn * 64 + n * 16 + m16;
    float bias = beff[col];
    f16_t* ob = (col < 256) ? khg : vhg;
    int oc = col & 255;
#pragma unroll
    for (int mt = 0; mt < 4; ++mt)
#pragma unroll
      for (int j = 0; j < 4; ++j) {
        int row = wm * 64 + mt * 16 + (g << 2) + j;
        int e = ebase + row;
        if (e < E) ob[(size_t)e * 256 + oc] = (f16_t)(acc[mt][n][j] + bias);
      }
  }
}

// ---------------------------------------------------------------------------
// k_agg: one wave per dst node (csr gather). Softmax without max-shift.
// ---------------------------------------------------------------------------
__global__ __launch_bounds__(256) void k_agg(
    const float* __restrict__ qhd, const f16_t* __restrict__ khs,
    const f16_t* __restrict__ vhs, const f16_t* __restrict__ khg,
    const f16_t* __restrict__ vhg, const int* __restrict__ rs,
    const int* __restrict__ csr, const float* __restrict__ lng,
    const float* __restrict__ lnb, float* __restrict__ out, int D) {
  const int lane = threadIdx.x & 63;
  const int d = blockIdx.x * 4 + (threadIdx.x >> 6);
  if (d >= D) return;
  const int c0 = lane * 4;

  float qh0, qh1, qh2, qh3;
  {
    float4 v = *(const float4*)(qhd + (size_t)d * 256 + c0);
    qh0 = v.x; qh1 = v.y; qh2 = v.z; qh3 = v.w;
  }

  float den, a0, a1, a2, a3;
  {
    f16x4 ku = *(const f16x4*)(khs + (size_t)d * 256 + c0);
    f16x4 vu = *(const f16x4*)(vhs + (size_t)d * 256 + c0);
    float s = qh0 * (float)ku[0] + qh1 * (float)ku[1] + qh2 * (float)ku[2] + qh3 * (float)ku[3];
    s += __shfl_xor(s, 1); s += __shfl_xor(s, 2); s += __shfl_xor(s, 4);
    s = (s > 0.f) ? s : 0.2f * s;
    float ee = __expf(s);
    den = ee;
    a0 = ee * (float)vu[0]; a1 = ee * (float)vu[1];
    a2 = ee * (float)vu[2]; a3 = ee * (float)vu[3];
  }

  const int beg = rs[d], end = rs[d + 1];
  f16x4 kN, vN;
  if (beg < end) {
    int e = csr[beg];
    kN = *(const f16x4*)(khg + (size_t)e * 256 + c0);
    vN = *(const f16x4*)(vhg + (size_t)e * 256 + c0);
  }
  for (int idx = beg; idx < end; ++idx) {
    f16x4 ku = kN, vu = vN;
    if (idx + 1 < end) {
      int e = csr[idx + 1];
      kN = *(const f16x4*)(khg + (size_t)e * 256 + c0);
      vN = *(const f16x4*)(vhg + (size_t)e * 256 + c0);
    }
    float s = qh0 * (float)ku[0] + qh1 * (float)ku[1] + qh2 * (float)ku[2] + qh3 * (float)ku[3];
    s += __shfl_xor(s, 1); s += __shfl_xor(s, 2); s += __shfl_xor(s, 4);
    s = (s > 0.f) ? s : 0.2f * s;
    float ee = __expf(s);
    den += ee;
    a0 = fmaf(ee, (float)vu[0], a0); a1 = fmaf(ee, (float)vu[1], a1);
    a2 = fmaf(ee, (float)vu[2], a2); a3 = fmaf(ee, (float)vu[3], a3);
  }

  float x0 = fmaxf(a0 / den, 0.f), x1 = fmaxf(a1 / den, 0.f);
  float x2 = fmaxf(a2 / den, 0.f), x3 = fmaxf(a3 / den, 0.f);

  float s1 = x0 + x1 + x2 + x3;
#pragma unroll
  for (int m = 1; m < 64; m <<= 1) s1 += __shfl_xor(s1, m);
  float mu = s1 * (1.f / 256.f);
  float d0 = x0 - mu, d1 = x1 - mu, d2 = x2 - mu, d3 = x3 - mu;
  float s2 = d0 * d0 + d1 * d1 + d2 * d2 + d3 * d3;
#pragma unroll
  for (int m = 1; m < 64; m <<= 1) s2 += __shfl_xor(s2, m);
  float rstd = rsqrtf(s2 * (1.f / 256.f) + 1e-5f);

  float4 gg = *(const float4*)(lng + c0);
  float4 bb = *(const float4*)(lnb + c0);
  float4 o;
  o.x = d0 * rstd * gg.x + bb.x;
  o.y = d1 * rstd * gg.y + bb.y;
  o.z = d2 * rstd * gg.z + bb.z;
  o.w = d3 * rstd * gg.w + bb.w;
  *(float4*)(out + (size_t)d * 256 + c0) = o;
}

// ---------------------------------------------------------------------------
extern "C" void kernel_launch(void* const* d_in, const int* in_sizes, int n_in,
                              void* d_out, int out_size, void* d_ws,
                              size_t ws_size, hipStream_t stream) {
  const float* h       = (const float*)d_in[0];
  const float* f       = (const float*)d_in[1];
  const float* dt      = (const float*)d_in[2];
  const float* wq_lin  = (const float*)d_in[3];
  const float* bq_lin  = (const float*)d_in[4];
  const float* wkv_lin = (const float*)d_in[5];
  const float* bkv_lin = (const float*)d_in[6];
  const float* wq      = (const float*)d_in[7];
  const float* bq      = (const float*)d_in[8];
  const float* wk      = (const float*)d_in[9];
  const float* bk      = (const float*)d_in[10];
  const float* wv      = (const float*)d_in[11];
  const float* bv      = (const float*)d_in[12];
  const float* lng     = (const float*)d_in[13];
  const float* lnb     = (const float*)d_in[14];
  const int*   dst     = (const int*)d_in[15];

  const int S = in_sizes[0] / 128;
  const int E = in_sizes[2];
  const int D = S - E;
  float* out = (float*)d_out;

  char* p = (char*)d_ws;
  size_t off = 0;
  auto take = [&](size_t bytes) -> char* {
    char* r = p + off;
    off += (bytes + 255) & ~(size_t)255;
    return r;
  };
  f16_t* wq1   = (f16_t*)take((size_t)32768 * 2);
  f16_t* w3    = (f16_t*)take((size_t)196608 * 2);
  float* bqe   = (float*)take((size_t)256 * 4);
  f16_t* weffp = (f16_t*)take((size_t)196608 * 2);
  float* beff  = (float*)take((size_t)512 * 4);
  float* qhd   = (float*)take((size_t)D * 256 * 4);
  f16_t* khs   = (f16_t*)take((size_t)D * 256 * 2);
  f16_t* vhs   = (f16_t*)take((size_t)D * 256 * 2);
  f16_t* khg   = (f16_t*)take((size_t)E * 256 * 2);
  f16_t* vhg   = (f16_t*)take((size_t)E * 256 * 2);
  int*   rs    = (int*)  take((size_t)(D + 1) * 4);
  int*   cur   = (int*)  take((size_t)D * 4);
  int*   csr   = (int*)  take((size_t)E * 4);

  if (off > ws_size) {
    k_sentinel<<<(out_size + 255) / 256, 256, 0, stream>>>(out, out_size);
    return;
  }

  hipMemsetAsync(rs, 0, (size_t)(D + 1) * 4, stream);
  k_prep<<<898, 256, 0, stream>>>(wq_lin, bq_lin, wq, wk, wv, wq1, w3, bqe);
  k_wcomp<<<512, 384, 0, stream>>>(wkv_lin, bkv_lin, wk, bk, wv, bv, weffp,
                                   beff);
  k_hist<<<(E + 255) / 256, 256, 0, stream>>>(dst, rs, E);
  k_scan<<<1, 1024, 0, stream>>>(rs, cur, D);
  k_scatter<<<(E + 255) / 256, 256, 0, stream>>>(dst, cur, csr, E);
  k_q<<<(D + 63) / 64, 512, 0, stream>>>(h, bqe, bq, bk, bv, wq1, w3, qhd, khs,
                                         vhs, D);
  k_kv<<<(E + 127) / 128, 1024, 0, stream>>>(h, f, dt, weffp, beff, khg, vhg,
                                             D, E);
  k_agg<<<(D + 3) / 4, 256, 0, stream>>>(qhd, khs, vhs, khg, vhg, rs, csr, lng,
                                         lnb, out, D);
}

// Round 5
// 782.044 us; speedup vs baseline: 1.9322x; 1.1598x over previous
//
#include <hip/hip_runtime.h>
#include <cstdint>
#include <cstddef>

// ---------------------------------------------------------------------------
// TGN transformer attention layer, MI355X (gfx950).
//   k_prep  : pack k_q weights to f16; bq_eff (time-ones folded)
//   k_wcomp : Weff = [Wk;Wv] @ Wkv (f32) -> f16 fragment-packed; beff
//   CSR     : hist/scan/scatter over dst
//   k_q     : D rows: Q_ori -> Qh(f32), Kh_self, Vh_self (f16)
//   k_kv    : single GEMM C[E x 512] = X[E x 384] @ Weff^T + beff.
//             Deep pipeline: global_load_lds staging, LDS triple-buffer,
//             raw s_barrier + counted vmcnt (loads fly across barriers),
//             LDS-staged coalesced C epilogue.
//   k_agg   : per-dst wave: segment softmax + weighted V sum + relu + LN
// ---------------------------------------------------------------------------

typedef _Float16 f16_t;
typedef _Float16 f16x8 __attribute__((ext_vector_type(8)));
typedef _Float16 f16x4 __attribute__((ext_vector_type(4)));
typedef float    f32x4 __attribute__((ext_vector_type(4)));

typedef unsigned int __attribute__((address_space(1))) gu32;
typedef unsigned int __attribute__((address_space(3))) lu32;

#define MFMA16(a, b, c) __builtin_amdgcn_mfma_f32_16x16x32_f16(a, b, c, 0, 0, 0)

static __device__ __forceinline__ void gload16(const void* g, void* l) {
  __builtin_amdgcn_global_load_lds((const gu32*)g, (lu32*)l, 16, 0, 0);
}

static __device__ __forceinline__ f32x4 zero4() {
  f32x4 v; v[0] = 0.f; v[1] = 0.f; v[2] = 0.f; v[3] = 0.f; return v;
}

// w_j = 10^(-9 j / 99)  ->  exp2(j * (-9*log2(10)/99))
#define TIMEW_LOG2 (-0.30199346317157837f)

// ---------------------------------------------------------------------------
__global__ void k_prep(const float* __restrict__ wq_lin,
                       const float* __restrict__ bq_lin,
                       const float* __restrict__ wq,
                       const float* __restrict__ wk,
                       const float* __restrict__ wv,
                       f16_t* __restrict__ wq1,
                       f16_t* __restrict__ w3,
                       float* __restrict__ bqe) {
  int i = blockIdx.x * 256 + threadIdx.x;
  if (i < 32768) {
    int o = i >> 7, k = i & 127;
    wq1[i] = (f16_t)wq_lin[o * 228 + k];
  } else if (i < 229376) {
    int j = i - 32768;
    int r = j >> 8, k = j & 255;
    const float* src = (r < 256) ? wq : ((r < 512) ? wk : wv);
    w3[j] = (f16_t)src[(r & 255) * 256 + k];
  } else if (i < 229632) {
    int o = i - 229376;
    float s = bq_lin[o];
    for (int j = 0; j < 100; ++j) s += wq_lin[o * 228 + 128 + j];
    bqe[o] = s;
  }
}

// ---------------------------------------------------------------------------
// k_wcomp: Weff[oc][c] = sum_m W23[oc][m] * Wkv[m][c]; packed:
//   idx = kc*16384 + g*4096 + oc*8 + j   (c = kc*32 + g*8 + j)
// ---------------------------------------------------------------------------
__global__ __launch_bounds__(384) void k_wcomp(
    const float* __restrict__ wkv_lin, const float* __restrict__ bkv,
    const float* __restrict__ wk, const float* __restrict__ bk,
    const float* __restrict__ wv, const float* __restrict__ bv,
    f16_t* __restrict__ weffp, float* __restrict__ beff) {
  __shared__ float wrow[256];
  const int oc = blockIdx.x;
  const float* src = (oc < 256) ? (wk + (size_t)oc * 256)
                                : (wv + (size_t)(oc - 256) * 256);
  const int t = threadIdx.x;
  if (t < 256) wrow[t] = src[t];
  __syncthreads();

  float acc = 0.f;
  if (t < 356) {
#pragma unroll 4
    for (int m = 0; m < 256; ++m) acc += wrow[m] * wkv_lin[(size_t)m * 356 + t];
  }
  int kc = t >> 5, g = (t >> 3) & 3, j = t & 7;
  weffp[(size_t)kc * 16384 + g * 4096 + oc * 8 + j] = (f16_t)acc;

  if (t == 0) {
    float b = (oc < 256) ? bk[oc] : bv[oc - 256];
    for (int m = 0; m < 256; ++m) b += wrow[m] * bkv[m];
    beff[oc] = b;
  }
}

// ---------------------------------------------------------------------------
// CSR build
// ---------------------------------------------------------------------------
__global__ void k_hist(const int* __restrict__ dst, int* __restrict__ rs, int E) {
  int e = blockIdx.x * 256 + threadIdx.x;
  if (e < E) atomicAdd(&rs[dst[e] + 1], 1);
}

__global__ void k_scan(int* __restrict__ rs, int* __restrict__ cur, int D) {
  __shared__ int sd[1024];
  __shared__ int srun;
  const int t = threadIdx.x;
  if (t == 0) srun = 0;
  __syncthreads();
  for (int base = 0; base < D; base += 1024) {
    const int i = base + t;
    int c = (i < D) ? rs[i + 1] : 0;
    sd[t] = c;
    __syncthreads();
    for (int off = 1; off < 1024; off <<= 1) {
      int v = (t >= off) ? sd[t - off] : 0;
      __syncthreads();
      sd[t] += v;
      __syncthreads();
    }
    const int incl = sd[t];
    const int run = srun;
    __syncthreads();
    if (i < D) {
      cur[i] = run + incl - c;
      rs[i + 1] = run + incl;
    }
    if (t == 1023) srun = run + sd[1023];
    __syncthreads();
  }
}

__global__ void k_scatter(const int* __restrict__ dst, int* __restrict__ cur,
                          int* __restrict__ csr, int E) {
  int e = blockIdx.x * 256 + threadIdx.x;
  if (e < E) {
    int pos = atomicAdd(&cur[dst[e]], 1);
    csr[pos] = e;
  }
}

__global__ void k_sentinel(float* __restrict__ o, int n) {
  int i = blockIdx.x * 256 + threadIdx.x;
  if (i < n) o[i] = 1e30f;
}

// ---------------------------------------------------------------------------
// k_q: 64 dst rows per block, 8 waves (small kernel, D=25k rows).
// ---------------------------------------------------------------------------
__global__ __launch_bounds__(512) void k_q(
    const float* __restrict__ h, const float* __restrict__ bqe,
    const float* __restrict__ bq, const float* __restrict__ bk,
    const float* __restrict__ bv, const f16_t* __restrict__ wq1,
    const f16_t* __restrict__ w3, float* __restrict__ qhd,
    f16_t* __restrict__ khs, f16_t* __restrict__ vhs, int D) {
  __shared__ f16_t sm[64 * 256];
  f16_t* xs = sm;
  f16_t* ks = sm;
  const int tid = threadIdx.x;
  const int dbase = blockIdx.x * 64;

  {
    const int r = tid >> 3, q = tid & 7;
    const int dd = min(dbase + r, D - 1);
    const int sw = r & 7;
    const float* p = h + (size_t)dd * 128 + q * 16;
#pragma unroll
    for (int u = 0; u < 2; ++u) {
      float4 v0 = *(const float4*)(p + u * 8);
      float4 v1 = *(const float4*)(p + u * 8 + 4);
      f16x8 w8;
      w8[0] = (f16_t)v0.x; w8[1] = (f16_t)v0.y; w8[2] = (f16_t)v0.z; w8[3] = (f16_t)v0.w;
      w8[4] = (f16_t)v1.x; w8[5] = (f16_t)v1.y; w8[6] = (f16_t)v1.z; w8[7] = (f16_t)v1.w;
      *(f16x8*)&xs[r * 128 + (((2 * q + u) ^ sw) << 3)] = w8;
    }
  }
  __syncthreads();

  const int lane = tid & 63;
  const int wv_ = tid >> 6;
  const int m16 = lane & 15;
  const int g = lane >> 4;

  f32x4 acc1[4][2];
#pragma unroll
  for (int mt = 0; mt < 4; ++mt)
#pragma unroll
    for (int nt = 0; nt < 2; ++nt) acc1[mt][nt] = zero4();

#pragma unroll
  for (int kt = 0; kt < 4; ++kt) {
    f16x8 a[4];
#pragma unroll
    for (int mt = 0; mt < 4; ++mt) {
      int row = mt * 16 + m16;
      a[mt] = *(const f16x8*)&xs[row * 128 + ((((kt << 2) + g) ^ (row & 7)) << 3)];
    }
#pragma unroll
    for (int nt = 0; nt < 2; ++nt) {
      int col = wv_ * 32 + nt * 16 + m16;
      f16x8 b = *(const f16x8*)&wq1[(size_t)col * 128 + (kt << 5) + (g << 3)];
#pragma unroll
      for (int mt = 0; mt < 4; ++mt) acc1[mt][nt] = MFMA16(a[mt], b, acc1[mt][nt]);
    }
  }
  __syncthreads();

#pragma unroll
  for (int nt = 0; nt < 2; ++nt) {
    int col = wv_ * 32 + nt * 16 + m16;
    float bias = bqe[col];
#pragma unroll
    for (int mt = 0; mt < 4; ++mt)
#pragma unroll
      for (int j = 0; j < 4; ++j) {
        int row = mt * 16 + (g << 2) + j;
        ks[row * 256 + ((((col >> 3) ^ (row & 7)) << 3)) + (col & 7)] =
            (f16_t)(acc1[mt][nt][j] + bias);
      }
  }
  __syncthreads();

#pragma unroll
  for (int p = 0; p < 3; ++p) {
    const f16_t* wsec = w3 + ((size_t)p << 16);
    const float* bsec = (p == 0) ? bq : ((p == 1) ? bk : bv);
    f32x4 acc[4][2];
#pragma unroll
    for (int mt = 0; mt < 4; ++mt)
#pragma unroll
      for (int nt = 0; nt < 2; ++nt) acc[mt][nt] = zero4();
#pragma unroll
    for (int kt = 0; kt < 8; ++kt) {
      f16x8 a[4];
#pragma unroll
      for (int mt = 0; mt < 4; ++mt) {
        int row = mt * 16 + m16;
        a[mt] = *(const f16x8*)&ks[row * 256 + ((((kt << 2) + g) ^ (row & 7)) << 3)];
      }
#pragma unroll
      for (int nt = 0; nt < 2; ++nt) {
        int col = wv_ * 32 + nt * 16 + m16;
        f16x8 b = *(const f16x8*)&wsec[(size_t)col * 256 + (kt << 5) + (g << 3)];
#pragma unroll
        for (int mt = 0; mt < 4; ++mt) acc[mt][nt] = MFMA16(a[mt], b, acc[mt][nt]);
      }
    }
#pragma unroll
    for (int nt = 0; nt < 2; ++nt) {
      int col = wv_ * 32 + nt * 16 + m16;
      float bias = bsec[col];
#pragma unroll
      for (int mt = 0; mt < 4; ++mt)
#pragma unroll
        for (int j = 0; j < 4; ++j) {
          int row = mt * 16 + (g << 2) + j;
          int dd = dbase + row;
          if (dd < D) {
            float val = acc[mt][nt][j] + bias;
            if (p == 0)
              qhd[(size_t)dd * 256 + col] = val;
            else if (p == 1)
              khs[(size_t)dd * 256 + col] = (f16_t)val;
            else
              vhs[(size_t)dd * 256 + col] = (f16_t)val;
          }
        }
    }
  }
}

// ---------------------------------------------------------------------------
// k_kv: C[E x 512] = X[E x 384] @ Weff^T + beff
//   BM=128, BN=512, BK=32, 1024 threads = 16 waves (wm 2 x wn 8, 64x64/wave)
//   LDS 144KB: A f32 3 x 16KB (XOR unit-swizzled via source addresses),
//              B f16 3 x 32KB (fragment-packed, linear gload).
//   Chunks 0..7: global_load_lds (h then f); chunks 8..11: computed cos ->
//   ds_write. Raw s_barrier + counted vmcnt -> loads in flight ~2 iters.
//   Epilogue: acc -> LDS [128][264] f16 -> coalesced full-line stores.
// ---------------------------------------------------------------------------
__global__ __launch_bounds__(1024, 4) void k_kv(
    const float* __restrict__ h, const float* __restrict__ f,
    const float* __restrict__ dt, const f16_t* __restrict__ weffp,
    const float* __restrict__ beff, f16_t* __restrict__ khg,
    f16_t* __restrict__ vhg, int D, int E) {
  __shared__ __align__(16) unsigned char smem[147456];  // 144 KB

  const int tid = threadIdx.x;
  const int ebase = blockIdx.x * 128;
  const int row = tid >> 3, q = tid & 7;
  const int sw = row & 7;
  const int squ = q ^ sw;                 // logical 16B-unit this thread fetches
  const int lane = tid & 63, wid = tid >> 6;
  const int wm = wid >> 3, wn = wid & 7;
  const int m16 = lane & 15, g = lane >> 4;
  const int ae = min(ebase + row, E - 1);
  const float dtv = dt[ae];

#define AF(b) ((float*)(smem + (b) * 16384))
#define BF(b) ((f16_t*)(smem + 49152 + (b) * 32768))

  // stage chunk kc into buffer kc%3
  auto stage = [&](int kc) {
    const int b = kc % 3;
    // B: 2 x global_load_lds, linear (weffp already fragment-packed)
    {
      const f16_t* gb = weffp + (size_t)kc * 16384 + wid * 1024 + lane * 8;
      f16_t* lb = BF(b) + wid * 1024;
      gload16(gb, lb);
      gload16(gb + 512, lb + 512);
    }
    if (kc < 8) {
      // A: 1 x global_load_lds per thread (f32, source XOR-swizzled)
      const float* ga = (kc < 4)
          ? (h + (size_t)(D + ae) * 128 + kc * 32 + squ * 4)
          : (f + (size_t)ae * 128 + (kc - 4) * 32 + squ * 4);
      gload16(ga, AF(b) + wid * 256);
    } else {
      // time features: compute cos, ds_write at linear (row,q) = logical squ
      float4 v;
      const int cb = (kc - 8) * 32 + squ * 4;
#pragma unroll
      for (int j = 0; j < 4; ++j) {
        int c = cb + j;
        float val = 0.f;
        if (c < 100) val = __cosf(dtv * exp2f(TIMEW_LOG2 * (float)c));
        ((float*)&v)[j] = val;
      }
      *(float4*)&AF(b)[row * 32 + q * 4] = v;
    }
  };

  f32x4 acc[4][4];
#pragma unroll
  for (int mt = 0; mt < 4; ++mt)
#pragma unroll
    for (int n = 0; n < 4; ++n) acc[mt][n] = zero4();

  // prologue: chunks 0 and 1 in flight; drain chunk 0 (leave chunk 1's 3 ops)
  stage(0);
  stage(1);
  asm volatile("s_waitcnt vmcnt(3) lgkmcnt(0)" ::: "memory");
  __builtin_amdgcn_sched_barrier(0);
  __builtin_amdgcn_s_barrier();
  __builtin_amdgcn_sched_barrier(0);

#pragma unroll
  for (int kc = 0; kc < 12; ++kc) {
    if (kc + 2 < 12) stage(kc + 2);

    const float* Ac = AF(kc % 3);
    const f16_t* Bc = BF(kc % 3);

    f16x8 bfr[4];
#pragma unroll
    for (int n = 0; n < 4; ++n)
      bfr[n] = *(const f16x8*)&Bc[g * 4096 + (wn * 64 + n * 16 + m16) * 8];

#pragma unroll
    for (int mt = 0; mt < 4; ++mt) {
      const int r2 = wm * 64 + mt * 16 + m16;
      const int ss = r2 & 7;
      float4 u0 = *(const float4*)&Ac[r2 * 32 + (((2 * g) ^ ss) << 2)];
      float4 u1 = *(const float4*)&Ac[r2 * 32 + (((2 * g + 1) ^ ss) << 2)];
      f16x8 afr;
      afr[0] = (f16_t)u0.x; afr[1] = (f16_t)u0.y; afr[2] = (f16_t)u0.z; afr[3] = (f16_t)u0.w;
      afr[4] = (f16_t)u1.x; afr[5] = (f16_t)u1.y; afr[6] = (f16_t)u1.z; afr[7] = (f16_t)u1.w;
#pragma unroll
      for (int n = 0; n < 4; ++n) acc[mt][n] = MFMA16(afr, bfr[n], acc[mt][n]);
    }

    if (kc < 11) {
      // drain up to (but not including) the chunk staged this iteration
      if (kc < 6) {
        asm volatile("s_waitcnt vmcnt(3) lgkmcnt(0)" ::: "memory");
      } else if (kc < 10) {
        asm volatile("s_waitcnt vmcnt(2) lgkmcnt(0)" ::: "memory");
      } else {
        asm volatile("s_waitcnt vmcnt(0) lgkmcnt(0)" ::: "memory");
      }
      __builtin_amdgcn_sched_barrier(0);
      __builtin_amdgcn_s_barrier();
      __builtin_amdgcn_sched_barrier(0);
    }
  }

  // ---- epilogue: stage C through LDS for coalesced full-line stores
  __builtin_amdgcn_s_barrier();  // all frag reads done; smem reusable
  f16_t* ep = (f16_t*)smem;      // [128][264] f16 = 66 KB

#pragma unroll
  for (int p = 0; p < 2; ++p) {
    if ((wn >> 2) == p) {
#pragma unroll
      for (int n = 0; n < 4; ++n) {
        const int c256 = (wn & 3) * 64 + n * 16 + m16;
        const float bias = beff[p * 256 + c256];
#pragma unroll
        for (int mt = 0; mt < 4; ++mt)
#pragma unroll
          for (int j = 0; j < 4; ++j) {
            const int r2 = wm * 64 + mt * 16 + (g << 2) + j;
            ep[r2 * 264 + c256] = (f16_t)(acc[mt][n][j] + bias);
          }
      }
    }
    asm volatile("s_waitcnt lgkmcnt(0)" ::: "memory");
    __builtin_amdgcn_s_barrier();

    f16_t* ob = p ? vhg : khg;
#pragma unroll
    for (int sweep = 0; sweep < 4; ++sweep) {
      const int flat = sweep * 8192 + tid * 8;
      const int r2 = flat >> 8, cc = flat & 255;
      const int e = ebase + r2;
      if (e < E) {
        f16x8 v = *(const f16x8*)&ep[r2 * 264 + cc];
        *(f16x8*)&ob[(size_t)e * 256 + cc] = v;
      }
    }
    if (p == 0) __builtin_amdgcn_s_barrier();  // reads done before pass-1 writes
  }
#undef AF
#undef BF
}

// ---------------------------------------------------------------------------
// k_agg: one wave per dst node (csr gather). Softmax without max-shift.
// ---------------------------------------------------------------------------
__global__ __launch_bounds__(256) void k_agg(
    const float* __restrict__ qhd, const f16_t* __restrict__ khs,
    const f16_t* __restrict__ vhs, const f16_t* __restrict__ khg,
    const f16_t* __restrict__ vhg, const int* __restrict__ rs,
    const int* __restrict__ csr, const float* __restrict__ lng,
    const float* __restrict__ lnb, float* __restrict__ out, int D) {
  const int lane = threadIdx.x & 63;
  const int d = blockIdx.x * 4 + (threadIdx.x >> 6);
  if (d >= D) return;
  const int c0 = lane * 4;

  float qh0, qh1, qh2, qh3;
  {
    float4 v = *(const float4*)(qhd + (size_t)d * 256 + c0);
    qh0 = v.x; qh1 = v.y; qh2 = v.z; qh3 = v.w;
  }

  float den, a0, a1, a2, a3;
  {
    f16x4 ku = *(const f16x4*)(khs + (size_t)d * 256 + c0);
    f16x4 vu = *(const f16x4*)(vhs + (size_t)d * 256 + c0);
    float s = qh0 * (float)ku[0] + qh1 * (float)ku[1] + qh2 * (float)ku[2] + qh3 * (float)ku[3];
    s += __shfl_xor(s, 1); s += __shfl_xor(s, 2); s += __shfl_xor(s, 4);
    s = (s > 0.f) ? s : 0.2f * s;
    float ee = __expf(s);
    den = ee;
    a0 = ee * (float)vu[0]; a1 = ee * (float)vu[1];
    a2 = ee * (float)vu[2]; a3 = ee * (float)vu[3];
  }

  const int beg = rs[d], end = rs[d + 1];
  f16x4 kN, vN;
  if (beg < end) {
    int e = csr[beg];
    kN = *(const f16x4*)(khg + (size_t)e * 256 + c0);
    vN = *(const f16x4*)(vhg + (size_t)e * 256 + c0);
  }
  for (int idx = beg; idx < end; ++idx) {
    f16x4 ku = kN, vu = vN;
    if (idx + 1 < end) {
      int e = csr[idx + 1];
      kN = *(const f16x4*)(khg + (size_t)e * 256 + c0);
      vN = *(const f16x4*)(vhg + (size_t)e * 256 + c0);
    }
    float s = qh0 * (float)ku[0] + qh1 * (float)ku[1] + qh2 * (float)ku[2] + qh3 * (float)ku[3];
    s += __shfl_xor(s, 1); s += __shfl_xor(s, 2); s += __shfl_xor(s, 4);
    s = (s > 0.f) ? s : 0.2f * s;
    float ee = __expf(s);
    den += ee;
    a0 = fmaf(ee, (float)vu[0], a0); a1 = fmaf(ee, (float)vu[1], a1);
    a2 = fmaf(ee, (float)vu[2], a2); a3 = fmaf(ee, (float)vu[3], a3);
  }

  float x0 = fmaxf(a0 / den, 0.f), x1 = fmaxf(a1 / den, 0.f);
  float x2 = fmaxf(a2 / den, 0.f), x3 = fmaxf(a3 / den, 0.f);

  float s1 = x0 + x1 + x2 + x3;
#pragma unroll
  for (int m = 1; m < 64; m <<= 1) s1 += __shfl_xor(s1, m);
  float mu = s1 * (1.f / 256.f);
  float d0 = x0 - mu, d1 = x1 - mu, d2 = x2 - mu, d3 = x3 - mu;
  float s2 = d0 * d0 + d1 * d1 + d2 * d2 + d3 * d3;
#pragma unroll
  for (int m = 1; m < 64; m <<= 1) s2 += __shfl_xor(s2, m);
  float rstd = rsqrtf(s2 * (1.f / 256.f) + 1e-5f);

  float4 gg = *(const float4*)(lng + c0);
  float4 bb = *(const float4*)(lnb + c0);
  float4 o;
  o.x = d0 * rstd * gg.x + bb.x;
  o.y = d1 * rstd * gg.y + bb.y;
  o.z = d2 * rstd * gg.z + bb.z;
  o.w = d3 * rstd * gg.w + bb.w;
  *(float4*)(out + (size_t)d * 256 + c0) = o;
}

// ---------------------------------------------------------------------------
extern "C" void kernel_launch(void* const* d_in, const int* in_sizes, int n_in,
                              void* d_out, int out_size, void* d_ws,
                              size_t ws_size, hipStream_t stream) {
  const float* h       = (const float*)d_in[0];
  const float* f       = (const float*)d_in[1];
  const float* dt      = (const float*)d_in[2];
  const float* wq_lin  = (const float*)d_in[3];
  const float* bq_lin  = (const float*)d_in[4];
  const float* wkv_lin = (const float*)d_in[5];
  const float* bkv_lin = (const float*)d_in[6];
  const float* wq      = (const float*)d_in[7];
  const float* bq      = (const float*)d_in[8];
  const float* wk      = (const float*)d_in[9];
  const float* bk      = (const float*)d_in[10];
  const float* wv      = (const float*)d_in[11];
  const float* bv      = (const float*)d_in[12];
  const float* lng     = (const float*)d_in[13];
  const float* lnb     = (const float*)d_in[14];
  const int*   dst     = (const int*)d_in[15];

  const int S = in_sizes[0] / 128;
  const int E = in_sizes[2];
  const int D = S - E;
  float* out = (float*)d_out;

  char* p = (char*)d_ws;
  size_t off = 0;
  auto take = [&](size_t bytes) -> char* {
    char* r = p + off;
    off += (bytes + 255) & ~(size_t)255;
    return r;
  };
  f16_t* wq1   = (f16_t*)take((size_t)32768 * 2);
  f16_t* w3    = (f16_t*)take((size_t)196608 * 2);
  float* bqe   = (float*)take((size_t)256 * 4);
  f16_t* weffp = (f16_t*)take((size_t)196608 * 2);
  float* beff  = (float*)take((size_t)512 * 4);
  float* qhd   = (float*)take((size_t)D * 256 * 4);
  f16_t* khs   = (f16_t*)take((size_t)D * 256 * 2);
  f16_t* vhs   = (f16_t*)take((size_t)D * 256 * 2);
  f16_t* khg   = (f16_t*)take((size_t)E * 256 * 2);
  f16_t* vhg   = (f16_t*)take((size_t)E * 256 * 2);
  int*   rs    = (int*)  take((size_t)(D + 1) * 4);
  int*   cur   = (int*)  take((size_t)D * 4);
  int*   csr   = (int*)  take((size_t)E * 4);

  if (off > ws_size) {
    k_sentinel<<<(out_size + 255) / 256, 256, 0, stream>>>(out, out_size);
    return;
  }

  hipMemsetAsync(rs, 0, (size_t)(D + 1) * 4, stream);
  k_prep<<<898, 256, 0, stream>>>(wq_lin, bq_lin, wq, wk, wv, wq1, w3, bqe);
  k_wcomp<<<512, 384, 0, stream>>>(wkv_lin, bkv_lin, wk, bk, wv, bv, weffp,
                                   beff);
  k_hist<<<(E + 255) / 256, 256, 0, stream>>>(dst, rs, E);
  k_scan<<<1, 1024, 0, stream>>>(rs, cur, D);
  k_scatter<<<(E + 255) / 256, 256, 0, stream>>>(dst, cur, csr, E);
  k_q<<<(D + 63) / 64, 512, 0, stream>>>(h, bqe, bq, bk, bv, wq1, w3, qhd, khs,
                                         vhs, D);
  k_kv<<<(E + 127) / 128, 1024, 0, stream>>>(h, f, dt, weffp, beff, khg, vhg,
                                             D, E);
  k_agg<<<(D + 3) / 4, 256, 0, stream>>>(qhd, khs, vhs, khg, vhg, rs, csr, lng,
                                         lnb, out, D);
}

// Round 6
// 715.987 us; speedup vs baseline: 2.1104x; 1.0923x over previous
//
#include <hip/hip_runtime.h>
#include <cstdint>
#include <cstddef>

// ---------------------------------------------------------------------------
// TGN transformer attention layer, MI355X (gfx950).
//   k_prep  : pack k_q weights to f16; bq_eff (time-ones folded)
//   k_wcomp : Weff = [Wk;Wv] @ Wkv (f32) -> f16 fragment-packed; beff
//   CSR     : hist/scan/scatter over dst
//   k_q     : D rows: Q_ori -> Qh(f32), Kh_self, Vh_self (f16)
//   k_kv    : single GEMM C[E x 512] = X[E x 384] @ Weff^T + beff.
//             B: global->VGPR from L2 (never in LDS).  A: reg-staged f16 into
//             stride-80B LDS rows, double-buffered, loads 3 chunks ahead.
//             One lgkm-only barrier per chunk (no vmcnt drains).
//   k_agg   : per-dst wave: segment softmax + weighted V sum + relu + LN
// ---------------------------------------------------------------------------

typedef _Float16 f16_t;
typedef _Float16 f16x8 __attribute__((ext_vector_type(8)));
typedef _Float16 f16x4 __attribute__((ext_vector_type(4)));
typedef float    f32x4 __attribute__((ext_vector_type(4)));

#define MFMA16(a, b, c) __builtin_amdgcn_mfma_f32_16x16x32_f16(a, b, c, 0, 0, 0)

static __device__ __forceinline__ f32x4 zero4() {
  f32x4 v; v[0] = 0.f; v[1] = 0.f; v[2] = 0.f; v[3] = 0.f; return v;
}

// w_j = 10^(-9 j / 99)  ->  exp2(j * (-9*log2(10)/99))
#define TIMEW_LOG2 (-0.30199346317157837f)

// ---------------------------------------------------------------------------
__global__ void k_prep(const float* __restrict__ wq_lin,
                       const float* __restrict__ bq_lin,
                       const float* __restrict__ wq,
                       const float* __restrict__ wk,
                       const float* __restrict__ wv,
                       f16_t* __restrict__ wq1,
                       f16_t* __restrict__ w3,
                       float* __restrict__ bqe) {
  int i = blockIdx.x * 256 + threadIdx.x;
  if (i < 32768) {
    int o = i >> 7, k = i & 127;
    wq1[i] = (f16_t)wq_lin[o * 228 + k];
  } else if (i < 229376) {
    int j = i - 32768;
    int r = j >> 8, k = j & 255;
    const float* src = (r < 256) ? wq : ((r < 512) ? wk : wv);
    w3[j] = (f16_t)src[(r & 255) * 256 + k];
  } else if (i < 229632) {
    int o = i - 229376;
    float s = bq_lin[o];
    for (int j = 0; j < 100; ++j) s += wq_lin[o * 228 + 128 + j];
    bqe[o] = s;
  }
}

// ---------------------------------------------------------------------------
// k_wcomp: Weff[oc][c] = sum_m W23[oc][m] * Wkv[m][c]; packed:
//   idx = kc*16384 + g*4096 + oc*8 + j   (c = kc*32 + g*8 + j)
// ---------------------------------------------------------------------------
__global__ __launch_bounds__(384) void k_wcomp(
    const float* __restrict__ wkv_lin, const float* __restrict__ bkv,
    const float* __restrict__ wk, const float* __restrict__ bk,
    const float* __restrict__ wv, const float* __restrict__ bv,
    f16_t* __restrict__ weffp, float* __restrict__ beff) {
  __shared__ float wrow[256];
  const int oc = blockIdx.x;
  const float* src = (oc < 256) ? (wk + (size_t)oc * 256)
                                : (wv + (size_t)(oc - 256) * 256);
  const int t = threadIdx.x;
  if (t < 256) wrow[t] = src[t];
  __syncthreads();

  float acc = 0.f;
  if (t < 356) {
#pragma unroll 4
    for (int m = 0; m < 256; ++m) acc += wrow[m] * wkv_lin[(size_t)m * 356 + t];
  }
  int kc = t >> 5, g = (t >> 3) & 3, j = t & 7;
  weffp[(size_t)kc * 16384 + g * 4096 + oc * 8 + j] = (f16_t)acc;

  if (t == 0) {
    float b = (oc < 256) ? bk[oc] : bv[oc - 256];
    for (int m = 0; m < 256; ++m) b += wrow[m] * bkv[m];
    beff[oc] = b;
  }
}

// ---------------------------------------------------------------------------
// CSR build
// ---------------------------------------------------------------------------
__global__ void k_hist(const int* __restrict__ dst, int* __restrict__ rs, int E) {
  int e = blockIdx.x * 256 + threadIdx.x;
  if (e < E) atomicAdd(&rs[dst[e] + 1], 1);
}

__global__ void k_scan(int* __restrict__ rs, int* __restrict__ cur, int D) {
  __shared__ int sd[1024];
  __shared__ int srun;
  const int t = threadIdx.x;
  if (t == 0) srun = 0;
  __syncthreads();
  for (int base = 0; base < D; base += 1024) {
    const int i = base + t;
    int c = (i < D) ? rs[i + 1] : 0;
    sd[t] = c;
    __syncthreads();
    for (int off = 1; off < 1024; off <<= 1) {
      int v = (t >= off) ? sd[t - off] : 0;
      __syncthreads();
      sd[t] += v;
      __syncthreads();
    }
    const int incl = sd[t];
    const int run = srun;
    __syncthreads();
    if (i < D) {
      cur[i] = run + incl - c;
      rs[i + 1] = run + incl;
    }
    if (t == 1023) srun = run + sd[1023];
    __syncthreads();
  }
}

__global__ void k_scatter(const int* __restrict__ dst, int* __restrict__ cur,
                          int* __restrict__ csr, int E) {
  int e = blockIdx.x * 256 + threadIdx.x;
  if (e < E) {
    int pos = atomicAdd(&cur[dst[e]], 1);
    csr[pos] = e;
  }
}

__global__ void k_sentinel(float* __restrict__ o, int n) {
  int i = blockIdx.x * 256 + threadIdx.x;
  if (i < n) o[i] = 1e30f;
}

// ---------------------------------------------------------------------------
// k_q: 64 dst rows per block, 8 waves (small kernel, D=25k rows).
// ---------------------------------------------------------------------------
__global__ __launch_bounds__(512) void k_q(
    const float* __restrict__ h, const float* __restrict__ bqe,
    const float* __restrict__ bq, const float* __restrict__ bk,
    const float* __restrict__ bv, const f16_t* __restrict__ wq1,
    const f16_t* __restrict__ w3, float* __restrict__ qhd,
    f16_t* __restrict__ khs, f16_t* __restrict__ vhs, int D) {
  __shared__ f16_t sm[64 * 256];
  f16_t* xs = sm;
  f16_t* ks = sm;
  const int tid = threadIdx.x;
  const int dbase = blockIdx.x * 64;

  {
    const int r = tid >> 3, q = tid & 7;
    const int dd = min(dbase + r, D - 1);
    const int sw = r & 7;
    const float* p = h + (size_t)dd * 128 + q * 16;
#pragma unroll
    for (int u = 0; u < 2; ++u) {
      float4 v0 = *(const float4*)(p + u * 8);
      float4 v1 = *(const float4*)(p + u * 8 + 4);
      f16x8 w8;
      w8[0] = (f16_t)v0.x; w8[1] = (f16_t)v0.y; w8[2] = (f16_t)v0.z; w8[3] = (f16_t)v0.w;
      w8[4] = (f16_t)v1.x; w8[5] = (f16_t)v1.y; w8[6] = (f16_t)v1.z; w8[7] = (f16_t)v1.w;
      *(f16x8*)&xs[r * 128 + (((2 * q + u) ^ sw) << 3)] = w8;
    }
  }
  __syncthreads();

  const int lane = tid & 63;
  const int wv_ = tid >> 6;
  const int m16 = lane & 15;
  const int g = lane >> 4;

  f32x4 acc1[4][2];
#pragma unroll
  for (int mt = 0; mt < 4; ++mt)
#pragma unroll
    for (int nt = 0; nt < 2; ++nt) acc1[mt][nt] = zero4();

#pragma unroll
  for (int kt = 0; kt < 4; ++kt) {
    f16x8 a[4];
#pragma unroll
    for (int mt = 0; mt < 4; ++mt) {
      int row = mt * 16 + m16;
      a[mt] = *(const f16x8*)&xs[row * 128 + ((((kt << 2) + g) ^ (row & 7)) << 3)];
    }
#pragma unroll
    for (int nt = 0; nt < 2; ++nt) {
      int col = wv_ * 32 + nt * 16 + m16;
      f16x8 b = *(const f16x8*)&wq1[(size_t)col * 128 + (kt << 5) + (g << 3)];
#pragma unroll
      for (int mt = 0; mt < 4; ++mt) acc1[mt][nt] = MFMA16(a[mt], b, acc1[mt][nt]);
    }
  }
  __syncthreads();

#pragma unroll
  for (int nt = 0; nt < 2; ++nt) {
    int col = wv_ * 32 + nt * 16 + m16;
    float bias = bqe[col];
#pragma unroll
    for (int mt = 0; mt < 4; ++mt)
#pragma unroll
      for (int j = 0; j < 4; ++j) {
        int row = mt * 16 + (g << 2) + j;
        ks[row * 256 + ((((col >> 3) ^ (row & 7)) << 3)) + (col & 7)] =
            (f16_t)(acc1[mt][nt][j] + bias);
      }
  }
  __syncthreads();

#pragma unroll
  for (int p = 0; p < 3; ++p) {
    const f16_t* wsec = w3 + ((size_t)p << 16);
    const float* bsec = (p == 0) ? bq : ((p == 1) ? bk : bv);
    f32x4 acc[4][2];
#pragma unroll
    for (int mt = 0; mt < 4; ++mt)
#pragma unroll
      for (int nt = 0; nt < 2; ++nt) acc[mt][nt] = zero4();
#pragma unroll
    for (int kt = 0; kt < 8; ++kt) {
      f16x8 a[4];
#pragma unroll
      for (int mt = 0; mt < 4; ++mt) {
        int row = mt * 16 + m16;
        a[mt] = *(const f16x8*)&ks[row * 256 + ((((kt << 2) + g) ^ (row & 7)) << 3)];
      }
#pragma unroll
      for (int nt = 0; nt < 2; ++nt) {
        int col = wv_ * 32 + nt * 16 + m16;
        f16x8 b = *(const f16x8*)&wsec[(size_t)col * 256 + (kt << 5) + (g << 3)];
#pragma unroll
        for (int mt = 0; mt < 4; ++mt) acc[mt][nt] = MFMA16(a[mt], b, acc[mt][nt]);
      }
    }
#pragma unroll
    for (int nt = 0; nt < 2; ++nt) {
      int col = wv_ * 32 + nt * 16 + m16;
      float bias = bsec[col];
#pragma unroll
      for (int mt = 0; mt < 4; ++mt)
#pragma unroll
        for (int j = 0; j < 4; ++j) {
          int row = mt * 16 + (g << 2) + j;
          int dd = dbase + row;
          if (dd < D) {
            float val = acc[mt][nt][j] + bias;
            if (p == 0)
              qhd[(size_t)dd * 256 + col] = val;
            else if (p == 1)
              khs[(size_t)dd * 256 + col] = (f16_t)val;
            else
              vhs[(size_t)dd * 256 + col] = (f16_t)val;
          }
        }
    }
  }
}

// ---------------------------------------------------------------------------
// k_kv: C[E x 512] = X[E x 384] @ Weff^T + beff
//   BM=128, BN=512, BK=32, 1024 threads = 16 waves (wm 2 x wn 8, 64x64/wave)
//   B: weffp fragment-packed, loaded global->VGPR (L2), dbuf 1 chunk ahead.
//   A: f32 global->reg (3 chunks ahead) -> cvt f16 -> ds_write, LDS rows
//      stride 80B (bank-clean), double-buffered.  Chunks 8..11 = cos features
//      computed in-register.  One lgkm-only s_barrier per chunk.
//   Epilogue: acc -> LDS [128][264] f16 (aliases A bufs) -> coalesced stores.
// ---------------------------------------------------------------------------
__global__ __launch_bounds__(1024, 4) void k_kv(
    const float* __restrict__ h, const float* __restrict__ f,
    const float* __restrict__ dt, const f16_t* __restrict__ weffp,
    const float* __restrict__ beff, f16_t* __restrict__ khg,
    f16_t* __restrict__ vhg, int D, int E) {
  __shared__ __align__(16) unsigned char smem[67584];  // 66 KB

  const int tid = threadIdx.x;
  const int ebase = blockIdx.x * 128;
  const int row = tid >> 3, q = tid & 7;
  const int lane = tid & 63, wid = tid >> 6;
  const int wm = wid >> 3, wn = wid & 7;
  const int m16 = lane & 15, g = lane >> 4;
  const int ae = min(ebase + row, E - 1);
  const float dtv = dt[ae];
  const float* hrow = h + (size_t)(D + ae) * 128 + q * 4;
  const float* frow = f + (size_t)ae * 128 + q * 4;

  // A chunk buffers: [buf][128 rows][40 f16] (80 B stride)
  auto abuf = [&](int b) -> f16_t* { return (f16_t*)(smem + b * 10240); };

  auto gldA = [&](int c) -> float4 {  // c < 8 only
    return (c < 4) ? *(const float4*)(hrow + c * 32)
                   : *(const float4*)(frow + (c - 4) * 32);
  };
  auto dswA = [&](int c, float4 v) {
    if (c >= 8) {
      const int cb = (c - 8) * 32 + q * 4;
#pragma unroll
      for (int j = 0; j < 4; ++j) {
        int cc = cb + j;
        ((float*)&v)[j] =
            (cc < 100) ? __cosf(dtv * exp2f(TIMEW_LOG2 * (float)cc)) : 0.f;
      }
    }
    f16x4 w;
    w[0] = (f16_t)v.x; w[1] = (f16_t)v.y; w[2] = (f16_t)v.z; w[3] = (f16_t)v.w;
    *(f16x4*)&abuf(c & 1)[row * 40 + q * 4] = w;
  };
  auto gldB = [&](int c, f16x8* dstB) {
    const f16_t* bb = weffp + (size_t)c * 16384 + g * 4096 + (wn * 64 + m16) * 8;
#pragma unroll
    for (int n = 0; n < 4; ++n) dstB[n] = *(const f16x8*)(bb + n * 128);
  };

  f32x4 acc[4][4];
#pragma unroll
  for (int mt = 0; mt < 4; ++mt)
#pragma unroll
    for (int n = 0; n < 4; ++n) acc[mt][n] = zero4();

  float4 aR[2];
  f16x8 bb[2][4];

  // prologue: chunks 0,1 loaded; chunk0 staged; chunk2 load in flight; B(0)
  aR[0] = gldA(0);
  aR[1] = gldA(1);
  gldB(0, bb[0]);
  dswA(0, aR[0]);
  aR[0] = gldA(2);
  asm volatile("s_waitcnt lgkmcnt(0)" ::: "memory");
  __builtin_amdgcn_sched_barrier(0);
  __builtin_amdgcn_s_barrier();
  __builtin_amdgcn_sched_barrier(0);

#pragma unroll
  for (int kc = 0; kc < 12; ++kc) {
    // stage next chunk's A into the other LDS buffer
    if (kc < 11) dswA(kc + 1, aR[(kc + 1) & 1]);
    // issue A global load 3 chunks ahead (only chunks < 8 come from memory)
    if (kc + 3 < 8) aR[(kc + 3) & 1] = gldA(kc + 3);
    // B prefetch one chunk ahead (L2-resident)
    if (kc < 11) gldB(kc + 1, bb[(kc + 1) & 1]);

    // MFMA on current chunk
    const f16_t* Ac = abuf(kc & 1);
#pragma unroll
    for (int mt = 0; mt < 4; ++mt) {
      const int r2 = wm * 64 + mt * 16 + m16;
      f16x8 afr = *(const f16x8*)&Ac[r2 * 40 + g * 8];
#pragma unroll
      for (int n = 0; n < 4; ++n)
        acc[mt][n] = MFMA16(afr, bb[kc & 1][n], acc[mt][n]);
    }

    asm volatile("s_waitcnt lgkmcnt(0)" ::: "memory");
    __builtin_amdgcn_sched_barrier(0);
    __builtin_amdgcn_s_barrier();
    __builtin_amdgcn_sched_barrier(0);
  }

  // ---- epilogue: stage C through LDS for coalesced full-line stores
  f16_t* ep = (f16_t*)smem;  // [128][264] f16 = 66 KB (A bufs dead)

#pragma unroll
  for (int p = 0; p < 2; ++p) {
    if ((wn >> 2) == p) {
#pragma unroll
      for (int n = 0; n < 4; ++n) {
        const int c256 = (wn & 3) * 64 + n * 16 + m16;
        const float bias = beff[p * 256 + c256];
#pragma unroll
        for (int mt = 0; mt < 4; ++mt)
#pragma unroll
          for (int j = 0; j < 4; ++j) {
            const int r2 = wm * 64 + mt * 16 + (g << 2) + j;
            ep[r2 * 264 + c256] = (f16_t)(acc[mt][n][j] + bias);
          }
      }
    }
    asm volatile("s_waitcnt lgkmcnt(0)" ::: "memory");
    __builtin_amdgcn_s_barrier();

    f16_t* ob = p ? vhg : khg;
#pragma unroll
    for (int sweep = 0; sweep < 4; ++sweep) {
      const int flat = sweep * 8192 + tid * 8;
      const int r2 = flat >> 8, cc = flat & 255;
      const int e = ebase + r2;
      if (e < E) {
        f16x8 v = *(const f16x8*)&ep[r2 * 264 + cc];
        *(f16x8*)&ob[(size_t)e * 256 + cc] = v;
      }
    }
    if (p == 0) __builtin_amdgcn_s_barrier();  // reads done before pass-1 writes
  }
}

// ---------------------------------------------------------------------------
// k_agg: one wave per dst node (csr gather). Softmax without max-shift.
// ---------------------------------------------------------------------------
__global__ __launch_bounds__(256) void k_agg(
    const float* __restrict__ qhd, const f16_t* __restrict__ khs,
    const f16_t* __restrict__ vhs, const f16_t* __restrict__ khg,
    const f16_t* __restrict__ vhg, const int* __restrict__ rs,
    const int* __restrict__ csr, const float* __restrict__ lng,
    const float* __restrict__ lnb, float* __restrict__ out, int D) {
  const int lane = threadIdx.x & 63;
  const int d = blockIdx.x * 4 + (threadIdx.x >> 6);
  if (d >= D) return;
  const int c0 = lane * 4;

  float qh0, qh1, qh2, qh3;
  {
    float4 v = *(const float4*)(qhd + (size_t)d * 256 + c0);
    qh0 = v.x; qh1 = v.y; qh2 = v.z; qh3 = v.w;
  }

  float den, a0, a1, a2, a3;
  {
    f16x4 ku = *(const f16x4*)(khs + (size_t)d * 256 + c0);
    f16x4 vu = *(const f16x4*)(vhs + (size_t)d * 256 + c0);
    float s = qh0 * (float)ku[0] + qh1 * (float)ku[1] + qh2 * (float)ku[2] + qh3 * (float)ku[3];
    s += __shfl_xor(s, 1); s += __shfl_xor(s, 2); s += __shfl_xor(s, 4);
    s = (s > 0.f) ? s : 0.2f * s;
    float ee = __expf(s);
    den = ee;
    a0 = ee * (float)vu[0]; a1 = ee * (float)vu[1];
    a2 = ee * (float)vu[2]; a3 = ee * (float)vu[3];
  }

  const int beg = rs[d], end = rs[d + 1];
  f16x4 kN, vN;
  if (beg < end) {
    int e = csr[beg];
    kN = *(const f16x4*)(khg + (size_t)e * 256 + c0);
    vN = *(const f16x4*)(vhg + (size_t)e * 256 + c0);
  }
  for (int idx = beg; idx < end; ++idx) {
    f16x4 ku = kN, vu = vN;
    if (idx + 1 < end) {
      int e = csr[idx + 1];
      kN = *(const f16x4*)(khg + (size_t)e * 256 + c0);
      vN = *(const f16x4*)(vhg + (size_t)e * 256 + c0);
    }
    float s = qh0 * (float)ku[0] + qh1 * (float)ku[1] + qh2 * (float)ku[2] + qh3 * (float)ku[3];
    s += __shfl_xor(s, 1); s += __shfl_xor(s, 2); s += __shfl_xor(s, 4);
    s = (s > 0.f) ? s : 0.2f * s;
    float ee = __expf(s);
    den += ee;
    a0 = fmaf(ee, (float)vu[0], a0); a1 = fmaf(ee, (float)vu[1], a1);
    a2 = fmaf(ee, (float)vu[2], a2); a3 = fmaf(ee, (float)vu[3], a3);
  }

  float x0 = fmaxf(a0 / den, 0.f), x1 = fmaxf(a1 / den, 0.f);
  float x2 = fmaxf(a2 / den, 0.f), x3 = fmaxf(a3 / den, 0.f);

  float s1 = x0 + x1 + x2 + x3;
#pragma unroll
  for (int m = 1; m < 64; m <<= 1) s1 += __shfl_xor(s1, m);
  float mu = s1 * (1.f / 256.f);
  float d0 = x0 - mu, d1 = x1 - mu, d2 = x2 - mu, d3 = x3 - mu;
  float s2 = d0 * d0 + d1 * d1 + d2 * d2 + d3 * d3;
#pragma unroll
  for (int m = 1; m < 64; m <<= 1) s2 += __shfl_xor(s2, m);
  float rstd = rsqrtf(s2 * (1.f / 256.f) + 1e-5f);

  float4 gg = *(const float4*)(lng + c0);
  float4 bb = *(const float4*)(lnb + c0);
  float4 o;
  o.x = d0 * rstd * gg.x + bb.x;
  o.y = d1 * rstd * gg.y + bb.y;
  o.z = d2 * rstd * gg.z + bb.z;
  o.w = d3 * rstd * gg.w + bb.w;
  *(float4*)(out + (size_t)d * 256 + c0) = o;
}

// ---------------------------------------------------------------------------
extern "C" void kernel_launch(void* const* d_in, const int* in_sizes, int n_in,
                              void* d_out, int out_size, void* d_ws,
                              size_t ws_size, hipStream_t stream) {
  const float* h       = (const float*)d_in[0];
  const float* f       = (const float*)d_in[1];
  const float* dt      = (const float*)d_in[2];
  const float* wq_lin  = (const float*)d_in[3];
  const float* bq_lin  = (const float*)d_in[4];
  const float* wkv_lin = (const float*)d_in[5];
  const float* bkv_lin = (const float*)d_in[6];
  const float* wq      = (const float*)d_in[7];
  const float* bq      = (const float*)d_in[8];
  const float* wk      = (const float*)d_in[9];
  const float* bk      = (const float*)d_in[10];
  const float* wv      = (const float*)d_in[11];
  const float* bv      = (const float*)d_in[12];
  const float* lng     = (const float*)d_in[13];
  const float* lnb     = (const float*)d_in[14];
  const int*   dst     = (const int*)d_in[15];

  const int S = in_sizes[0] / 128;
  const int E = in_sizes[2];
  const int D = S - E;
  float* out = (float*)d_out;

  char* p = (char*)d_ws;
  size_t off = 0;
  auto take = [&](size_t bytes) -> char* {
    char* r = p + off;
    off += (bytes + 255) & ~(size_t)255;
    return r;
  };
  f16_t* wq1   = (f16_t*)take((size_t)32768 * 2);
  f16_t* w3    = (f16_t*)take((size_t)196608 * 2);
  float* bqe   = (float*)take((size_t)256 * 4);
  f16_t* weffp = (f16_t*)take((size_t)196608 * 2);
  float* beff  = (float*)take((size_t)512 * 4);
  float* qhd   = (float*)take((size_t)D * 256 * 4);
  f16_t* khs   = (f16_t*)take((size_t)D * 256 * 2);
  f16_t* vhs   = (f16_t*)take((size_t)D * 256 * 2);
  f16_t* khg   = (f16_t*)take((size_t)E * 256 * 2);
  f16_t* vhg   = (f16_t*)take((size_t)E * 256 * 2);
  int*   rs    = (int*)  take((size_t)(D + 1) * 4);
  int*   cur   = (int*)  take((size_t)D * 4);
  int*   csr   = (int*)  take((size_t)E * 4);

  if (off > ws_size) {
    k_sentinel<<<(out_size + 255) / 256, 256, 0, stream>>>(out, out_size);
    return;
  }

  hipMemsetAsync(rs, 0, (size_t)(D + 1) * 4, stream);
  k_prep<<<898, 256, 0, stream>>>(wq_lin, bq_lin, wq, wk, wv, wq1, w3, bqe);
  k_wcomp<<<512, 384, 0, stream>>>(wkv_lin, bkv_lin, wk, bk, wv, bv, weffp,
                                   beff);
  k_hist<<<(E + 255) / 256, 256, 0, stream>>>(dst, rs, E);
  k_scan<<<1, 1024, 0, stream>>>(rs, cur, D);
  k_scatter<<<(E + 255) / 256, 256, 0, stream>>>(dst, cur, csr, E);
  k_q<<<(D + 63) / 64, 512, 0, stream>>>(h, bqe, bq, bk, bv, wq1, w3, qhd, khs,
                                         vhs, D);
  k_kv<<<(E + 127) / 128, 1024, 0, stream>>>(h, f, dt, weffp, beff, khg, vhg,
                                             D, E);
  k_agg<<<(D + 3) / 4, 256, 0, stream>>>(qhd, khs, vhs, khg, vhg, rs, csr, lng,
                                         lnb, out, D);
}